// Round 7
// baseline (176.568 us; speedup 1.0000x reference)
//
#include <hip/hip_runtime.h>

#define EMBED 1024
#define NTOK  4096
#define MARGIN 256.0f   // i8 cheap-logit error sigma ~22; 2*5.5sigma + window
#define KC     8        // candidate slots per (row, wave-tile)
#define CAP    128      // final per-row candidate cap

// i8 scales: Xi8 = round(X * 127/5), Qi8 = round(Q' * 127/8192)
#define SX_INV 25.4f
#define SQ_INV 0.0155029296875f
#define SCLOGIT 0.07936198f   // (8192/127)*(5/127)/32

typedef short  s16x8 __attribute__((ext_vector_type(8)));
typedef float  f32x4 __attribute__((ext_vector_type(4)));
typedef int    i32x4 __attribute__((ext_vector_type(4)));

// ---- bf16 helpers (RNE) ----------------------------------------------------
__device__ __forceinline__ unsigned short f2bf(float f) {
    unsigned int u = __float_as_uint(f);
    u = (u + 0x7FFFu + ((u >> 16) & 1u)) >> 16;
    return (unsigned short)u;
}
__device__ __forceinline__ float bf2f(unsigned short h) {
    return __uint_as_float(((unsigned int)h) << 16);
}

// ---- async 16B global->LDS -------------------------------------------------
__device__ __forceinline__ void async16(const void* g, void* l) {
    __builtin_amdgcn_global_load_lds(
        (const __attribute__((address_space(1))) unsigned int*)g,
        (__attribute__((address_space(3))) unsigned int*)l, 16, 0, 0);
}

// Stage ROWS x 64-byte rows (row-major, swizzled 16B chunks) into LDS.
// ld in BYTES. 4-wave (256-thread) version.
template<int ROWS>
__device__ __forceinline__ void stage_rows(const char* __restrict__ g,
                                           int ld, char* lds, int wave, int lane) {
#pragma unroll
    for (int r = 0; r < ROWS / 64; ++r) {
        const int row0 = (wave * (ROWS / 64) + r) * 16;   // wave-uniform
        const int r_loc = lane >> 2;
        const int kc = (lane - (lane >> 3)) & 3;          // (slot - r_loc/2) & 3
        const char* gp = g + (size_t)(row0 + r_loc) * ld + kc * 16;
        char* lp = lds + row0 * 64;                       // wave-uniform base
        async16(gp, lp);
    }
}

// 8-wave (512-thread) version. ROWS must be a multiple of 128.
template<int ROWS>
__device__ __forceinline__ void stage_rows8(const char* __restrict__ g,
                                            int ld, char* lds, int wave, int lane) {
#pragma unroll
    for (int r = 0; r < ROWS / 128; ++r) {
        const int row0 = (wave * (ROWS / 128) + r) * 16;  // wave-uniform
        const int r_loc = lane >> 2;
        const int kc = (lane - (lane >> 3)) & 3;
        const char* gp = g + (size_t)(row0 + r_loc) * ld + kc * 16;
        char* lp = lds + row0 * 64;                       // wave-uniform base
        async16(gp, lp);
    }
}

__device__ __forceinline__ int frag_slot(int row, int kc) {
    return (kc + ((row & 15) >> 1)) & 3;
}
__device__ __forceinline__ s16x8 frag_bf16(const char* lds, int row, int kc) {
    return *(const s16x8*)(lds + row * 64 + frag_slot(row, kc) * 16);
}
__device__ __forceinline__ i32x4 frag_i8(const char* lds, int row, int kc) {
    return *(const i32x4*)(lds + row * 64 + frag_slot(row, kc) * 16);
}

// ---------------------------------------------------------------------------
// prep_w: W -> bf16 hi/lo splits only (the T GEMM's operands).
// 2048 blocks x 256 threads (~24 MB, ~4 us).
// ---------------------------------------------------------------------------
__global__ __launch_bounds__(256) void prep_w(
        const float4* __restrict__ Wq, const float4* __restrict__ Wk,
        ushort4* __restrict__ Wqhi, ushort4* __restrict__ Wqlo,
        ushort4* __restrict__ Wkhi, ushort4* __restrict__ Wklo) {
    const int NW4 = EMBED * EMBED / 4;
    const int n = blockIdx.x * 256 + threadIdx.x;

    const float4* src;
    ushort4 *hi, *lo;
    int idx;
    if (n < NW4) { src = Wq; hi = Wqhi; lo = Wqlo; idx = n; }
    else         { src = Wk; hi = Wkhi; lo = Wklo; idx = n - NW4; }
    const float4 v = src[idx];
    ushort4 h, l;
    h.x = f2bf(v.x); l.x = f2bf(v.x - bf2f(h.x));
    h.y = f2bf(v.y); l.y = f2bf(v.y - bf2f(h.y));
    h.z = f2bf(v.z); l.z = f2bf(v.z - bf2f(h.z));
    h.w = f2bf(v.w); l.w = f2bf(v.w - bf2f(h.w));
    hi[idx] = h; lo[idx] = l;
}

// ---------------------------------------------------------------------------
// Fused dispatch: split-K=4 T-partial GEMM (z<4) + X split (z>=4).
// T = Wk @ Wq^T, 3-pass split bf16, 64x64 tile, K-slice = 256 per z.
// Partials to Cpart[z] (fp32, no atomics). X-split blocks (BW-bound) overlap
// the latency-bound GEMM blocks (m114 MFMA+mem co-scheduling).
// grid (16,16,20), 256 threads.
// ---------------------------------------------------------------------------
__global__ __launch_bounds__(256) void t_fused(
        const unsigned short* __restrict__ Ahi, const unsigned short* __restrict__ Alo,
        const unsigned short* __restrict__ Bhi, const unsigned short* __restrict__ Blo,
        float* __restrict__ Cpart,
        const float4* __restrict__ X, ushort4* __restrict__ Xhi,
        ushort4* __restrict__ Xlo, char4* __restrict__ Xi8)
{
    constexpr int BM = 64, BN = 64, NCH = 2;
    __shared__ __align__(16) char As_hi[BM * 64 * NCH];
    __shared__ __align__(16) char Bs_hi[BN * 64 * NCH];
    __shared__ __align__(16) char As_lo[BM * 64 * NCH];
    __shared__ __align__(16) char Bs_lo[BN * 64 * NCH];

    const int t = threadIdx.x;
    const int z = blockIdx.z;

    if (z >= 4) {
        // ---- X split branch: 4096 blocks x 256 threads, 1 float4 each ----
        const int idx = (((z - 4) * 256) + blockIdx.y * 16 + blockIdx.x) * 256 + t;
        const float4 v = X[idx];
        ushort4 h, l;
        h.x = f2bf(v.x); l.x = f2bf(v.x - bf2f(h.x));
        h.y = f2bf(v.y); l.y = f2bf(v.y - bf2f(h.y));
        h.z = f2bf(v.z); l.z = f2bf(v.z - bf2f(h.z));
        h.w = f2bf(v.w); l.w = f2bf(v.w - bf2f(h.w));
        Xhi[idx] = h; Xlo[idx] = l;
        char4 c;
        c.x = (signed char)(int)rintf(fminf(fmaxf(v.x * SX_INV, -127.f), 127.f));
        c.y = (signed char)(int)rintf(fminf(fmaxf(v.y * SX_INV, -127.f), 127.f));
        c.z = (signed char)(int)rintf(fminf(fmaxf(v.z * SX_INV, -127.f), 127.f));
        c.w = (signed char)(int)rintf(fminf(fmaxf(v.w * SX_INV, -127.f), 127.f));
        Xi8[idx] = c;
        return;
    }

    // ---- T-partial GEMM branch: K in [z*256, z*256+256) ----
    const int lane = t & 63, wave = t >> 6;
    const int wm = wave >> 1, wn = wave & 1;
    const int m0 = blockIdx.y * BM, n0 = blockIdx.x * BN;

    f32x4 acc[2][2];
#pragma unroll
    for (int i = 0; i < 2; ++i)
#pragma unroll
        for (int j = 0; j < 2; ++j)
#pragma unroll
            for (int r = 0; r < 4; ++r) acc[i][j][r] = 0.f;

    const char* ah_g = (const char*)(Ahi + (size_t)m0 * EMBED);
    const char* bh_g = (const char*)(Bhi + (size_t)n0 * EMBED);
    const char* al_g = (const char*)(Alo + (size_t)m0 * EMBED);
    const char* bl_g = (const char*)(Blo + (size_t)n0 * EMBED);

    const int kc = lane >> 4;
    const int rr = lane & 15;
    const int kbeg = z * 256;

    for (int k0 = kbeg; k0 < kbeg + 256; k0 += 32 * NCH) {
#pragma unroll
        for (int c = 0; c < NCH; ++c) {
            const int kb = (k0 + 32 * c) * 2;
            stage_rows<BM>(ah_g + kb, EMBED * 2, As_hi + c * BM * 64, wave, lane);
            stage_rows<BN>(bh_g + kb, EMBED * 2, Bs_hi + c * BN * 64, wave, lane);
            stage_rows<BM>(al_g + kb, EMBED * 2, As_lo + c * BM * 64, wave, lane);
            stage_rows<BN>(bl_g + kb, EMBED * 2, Bs_lo + c * BN * 64, wave, lane);
        }
        __syncthreads();

#pragma unroll
        for (int c = 0; c < NCH; ++c) {
            s16x8 ah[2], bh[2], al[2], bl[2];
#pragma unroll
            for (int i = 0; i < 2; ++i)
                ah[i] = frag_bf16(As_hi + c * BM * 64, wm * 32 + i * 16 + rr, kc);
#pragma unroll
            for (int j = 0; j < 2; ++j)
                bh[j] = frag_bf16(Bs_hi + c * BN * 64, wn * 32 + j * 16 + rr, kc);
#pragma unroll
            for (int i = 0; i < 2; ++i)
                al[i] = frag_bf16(As_lo + c * BM * 64, wm * 32 + i * 16 + rr, kc);
#pragma unroll
            for (int j = 0; j < 2; ++j)
                bl[j] = frag_bf16(Bs_lo + c * BN * 64, wn * 32 + j * 16 + rr, kc);

#pragma unroll
            for (int i = 0; i < 2; ++i)
#pragma unroll
                for (int j = 0; j < 2; ++j)
                    acc[i][j] = __builtin_amdgcn_mfma_f32_16x16x32_bf16(ah[i], bh[j], acc[i][j], 0, 0, 0);
#pragma unroll
            for (int i = 0; i < 2; ++i)
#pragma unroll
                for (int j = 0; j < 2; ++j)
                    acc[i][j] = __builtin_amdgcn_mfma_f32_16x16x32_bf16(ah[i], bl[j], acc[i][j], 0, 0, 0);
#pragma unroll
            for (int i = 0; i < 2; ++i)
#pragma unroll
                for (int j = 0; j < 2; ++j)
                    acc[i][j] = __builtin_amdgcn_mfma_f32_16x16x32_bf16(al[i], bh[j], acc[i][j], 0, 0, 0);
        }
        __syncthreads();
    }

    // fp32 partial epilogue into slice z
    const int lr = lane >> 4;
    const int lc = lane & 15;
    float* Cz = Cpart + (size_t)z * EMBED * EMBED;
#pragma unroll
    for (int i = 0; i < 2; ++i)
#pragma unroll
        for (int j = 0; j < 2; ++j)
#pragma unroll
            for (int r = 0; r < 4; ++r) {
                const int row = m0 + wm * 32 + i * 16 + lr * 4 + r;
                const int col = n0 + wn * 32 + j * 16 + lc;
                Cz[(size_t)row * EMBED + col] = acc[i][j][r];
            }
}

// ---------------------------------------------------------------------------
// Merge 4 fp32 T-partials -> split bf16 (Thi, Tlo). 1024 blocks x 256 thr.
// ---------------------------------------------------------------------------
__global__ __launch_bounds__(256) void t_merge(const float4* __restrict__ P,
                                               ushort4* __restrict__ Thi,
                                               ushort4* __restrict__ Tlo) {
    const int idx = blockIdx.x * 256 + threadIdx.x;   // over EMBED*EMBED/4
    const int S = EMBED * EMBED / 4;
    const float4 a = P[idx], b = P[idx + S], c = P[idx + 2 * S], d = P[idx + 3 * S];
    float4 s;
    s.x = (a.x + b.x) + (c.x + d.x);
    s.y = (a.y + b.y) + (c.y + d.y);
    s.z = (a.z + b.z) + (c.z + d.z);
    s.w = (a.w + b.w) + (c.w + d.w);
    ushort4 h, l;
    h.x = f2bf(s.x); l.x = f2bf(s.x - bf2f(h.x));
    h.y = f2bf(s.y); l.y = f2bf(s.y - bf2f(h.y));
    h.z = f2bf(s.z); l.z = f2bf(s.z - bf2f(h.z));
    h.w = f2bf(s.w); l.w = f2bf(s.w - bf2f(h.w));
    Thi[idx] = h; Tlo[idx] = l;
}

// ---------------------------------------------------------------------------
// Qf GEMM: Qf[4096,1024] = X[4096,1024] @ T^T, 3-pass split bf16 (hh+hl+lh).
// ALL operands bf16 in memory, staged via global_load_lds — zero cvt VALU.
// m97-style 2-barrier loop. 512 threads / 8 waves, per-wave 32x32 tile,
// LDS 48 KB -> 3 blocks/CU. XCD-aware bijective swizzle.
// Epilogue: fp32 Qf + i8 Qi8. (R5 config — measured best.)
// ---------------------------------------------------------------------------
__global__ __launch_bounds__(512) void qf_gemm(
        const unsigned short* __restrict__ Ahi, const unsigned short* __restrict__ Alo,
        const unsigned short* __restrict__ Bhi, const unsigned short* __restrict__ Blo,
        float* __restrict__ C, signed char* __restrict__ Ci8)
{
    constexpr int BM = 128, BN = 64, NCH = 2;             // K-step = 64
    __shared__ __align__(16) char As_hi[BM * 64 * NCH];   // 16 KB
    __shared__ __align__(16) char As_lo[BM * 64 * NCH];   // 16 KB
    __shared__ __align__(16) char Bs_hi[BN * 64 * NCH];   // 8 KB
    __shared__ __align__(16) char Bs_lo[BN * 64 * NCH];   // 8 KB

    const int t = threadIdx.x;
    const int lane = t & 63, wave = t >> 6;
    const int wm = wave >> 1, wn = wave & 1;              // 4x2 wave grid

    // XCD swizzle: 512 blocks = 8 XCD x 64; per XCD 4 m-panels x 16 n-tiles
    const int bid = blockIdx.y * 16 + blockIdx.x;
    const int g = bid & 7, ii = bid >> 3;                 // ii in 0..63
    const int m0 = (g * 4 + (ii >> 4)) * BM;
    const int n0 = (ii & 15) * BN;

    f32x4 acc[2][2];
#pragma unroll
    for (int i = 0; i < 2; ++i)
#pragma unroll
        for (int j = 0; j < 2; ++j)
#pragma unroll
            for (int r = 0; r < 4; ++r) acc[i][j][r] = 0.f;

    const char* ah_g = (const char*)(Ahi + (size_t)m0 * EMBED);
    const char* al_g = (const char*)(Alo + (size_t)m0 * EMBED);

    // B staging: waves 0-3 stage Bs_hi, waves 4-7 stage Bs_lo (16 rows each)
    const unsigned short* bsrc = (wave < 4) ? Bhi : Blo;
    char* bdst = (wave < 4) ? Bs_hi : Bs_lo;
    const int w4 = wave & 3;
    const int brow0 = w4 * 16;
    const int b_rloc = lane >> 2;
    const int b_kc = (lane - (lane >> 3)) & 3;
    const char* bg = (const char*)(bsrc + (size_t)(n0 + brow0 + b_rloc) * EMBED) + b_kc * 16;
    char* b_lds = bdst + brow0 * 64;                      // wave-uniform

    const int kc = lane >> 4;
    const int rr = lane & 15;

    for (int k0 = 0; k0 < EMBED; k0 += 32 * NCH) {
#pragma unroll
        for (int c = 0; c < NCH; ++c) {
            const int kb = (k0 + 32 * c) * 2;
            stage_rows8<BM>(ah_g + kb, EMBED * 2, As_hi + c * BM * 64, wave, lane);
            stage_rows8<BM>(al_g + kb, EMBED * 2, As_lo + c * BM * 64, wave, lane);
            async16(bg + kb, b_lds + c * BN * 64);
        }
        __syncthreads();

#pragma unroll
        for (int c = 0; c < NCH; ++c) {
            s16x8 ah[2], bh[2], al[2], bl[2];
#pragma unroll
            for (int i = 0; i < 2; ++i)
                ah[i] = frag_bf16(As_hi + c * BM * 64, wm * 32 + i * 16 + rr, kc);
#pragma unroll
            for (int j = 0; j < 2; ++j)
                bh[j] = frag_bf16(Bs_hi + c * BN * 64, wn * 32 + j * 16 + rr, kc);
#pragma unroll
            for (int i = 0; i < 2; ++i)
                al[i] = frag_bf16(As_lo + c * BM * 64, wm * 32 + i * 16 + rr, kc);
#pragma unroll
            for (int j = 0; j < 2; ++j)
                bl[j] = frag_bf16(Bs_lo + c * BN * 64, wn * 32 + j * 16 + rr, kc);

#pragma unroll
            for (int i = 0; i < 2; ++i)
#pragma unroll
                for (int j = 0; j < 2; ++j)
                    acc[i][j] = __builtin_amdgcn_mfma_f32_16x16x32_bf16(ah[i], bh[j], acc[i][j], 0, 0, 0);
#pragma unroll
            for (int i = 0; i < 2; ++i)
#pragma unroll
                for (int j = 0; j < 2; ++j)
                    acc[i][j] = __builtin_amdgcn_mfma_f32_16x16x32_bf16(ah[i], bl[j], acc[i][j], 0, 0, 0);
#pragma unroll
            for (int i = 0; i < 2; ++i)
#pragma unroll
                for (int j = 0; j < 2; ++j)
                    acc[i][j] = __builtin_amdgcn_mfma_f32_16x16x32_bf16(al[i], bh[j], acc[i][j], 0, 0, 0);
        }
        __syncthreads();
    }

    // Epilogue: C/D layout col=lane&15, row=(lane>>4)*4+reg
    const int lr = lane >> 4;
    const int lc = lane & 15;
#pragma unroll
    for (int i = 0; i < 2; ++i)
#pragma unroll
        for (int j = 0; j < 2; ++j)
#pragma unroll
            for (int r = 0; r < 4; ++r) {
                const int row = m0 + wm * 32 + i * 16 + lr * 4 + r;
                const int col = n0 + wn * 32 + j * 16 + lc;
                const float v = acc[i][j][r];
                const size_t idx = (size_t)row * EMBED + col;
                C[idx] = v;
                const float q = fminf(fmaxf(v * SQ_INV, -127.f), 127.f);
                Ci8[idx] = (signed char)(int)rintf(q);
            }
}

// ---------------------------------------------------------------------------
// i8 scores GEMM + write-only candidate selection. m97 2-barrier loop,
// K-step 128. 256x128 tile, 512 threads / 8 waves, LDS 48 KB -> 2 blocks/CU,
// 512 blocks fully co-resident. XCD swizzle: 8 XCD x (2 m-panels x 32 n).
// (R4/R5 config — measured stable.)
// ---------------------------------------------------------------------------
__global__ __launch_bounds__(512, 4) void gemm_i8_scores(
        const signed char* __restrict__ A,   // Qi8 [NTOK, EMBED]
        const signed char* __restrict__ B,   // Xi8 [NTOK, EMBED]
        float* __restrict__ tmax, int* __restrict__ cnts, int2* __restrict__ cand)
{
    __shared__ __align__(16) char As[256 * 64 * 2];   // 32 KB
    __shared__ __align__(16) char Bs[128 * 64 * 2];   // 16 KB

    const int t = threadIdx.x;
    const int lane = t & 63, wave = t >> 6;
    const int wm = wave >> 1, wn = wave & 1;          // 4x2 wave grid

    // XCD swizzle: 512 blocks = 8 XCD x 64; per XCD 2 m-panels x 32 n-tiles
    const int bid = blockIdx.y * 32 + blockIdx.x;
    const int g = bid & 7, ii = bid >> 3;             // ii in 0..63
    const int by = g * 2 + (ii >> 5);
    const int bx = ii & 31;
    const int m0 = by * 256, n0 = bx * 128;

    i32x4 acc[4][4];
#pragma unroll
    for (int i = 0; i < 4; ++i)
#pragma unroll
        for (int j = 0; j < 4; ++j)
#pragma unroll
            for (int r = 0; r < 4; ++r) acc[i][j][r] = 0;

    const char* a_g = (const char*)A + (size_t)m0 * EMBED;
    const char* b_g = (const char*)B + (size_t)n0 * EMBED;
    const int kc = lane >> 4;
    const int rr = lane & 15;

    for (int k0 = 0; k0 < EMBED; k0 += 128) {
#pragma unroll
        for (int c = 0; c < 2; ++c) {
            stage_rows8<256>(a_g + k0 + 64 * c, EMBED, As + c * 256 * 64, wave, lane);
            stage_rows8<128>(b_g + k0 + 64 * c, EMBED, Bs + c * 128 * 64, wave, lane);
        }
        __syncthreads();

#pragma unroll
        for (int c = 0; c < 2; ++c) {
            i32x4 af[4], bf[4];
#pragma unroll
            for (int i = 0; i < 4; ++i) af[i] = frag_i8(As + c * 256 * 64, wm * 64 + i * 16 + rr, kc);
#pragma unroll
            for (int j = 0; j < 4; ++j) bf[j] = frag_i8(Bs + c * 128 * 64, wn * 64 + j * 16 + rr, kc);
#pragma unroll
            for (int i = 0; i < 4; ++i)
#pragma unroll
                for (int j = 0; j < 4; ++j)
                    acc[i][j] = __builtin_amdgcn_mfma_i32_16x16x64_i8(af[i], bf[j], acc[i][j], 0, 0, 0);
        }
        __syncthreads();
    }

    // Write-only local selection epilogue (per-wave 64x64 — unchanged).
    const int lr = lane >> 4;
    const int lc = lane & 15;
    const int wslot = bx * 2 + wn;                    // 64 slots per row
    const unsigned long long grp = 0xFFFFull << (lr * 16);
    const unsigned long long low = (lane == 63) ? 0x7FFFFFFFFFFFFFFFull
                                                : ((1ull << lane) - 1);
#pragma unroll
    for (int i = 0; i < 4; ++i)
#pragma unroll
        for (int r = 0; r < 4; ++r) {
            const int row = m0 + wm * 64 + i * 16 + lr * 4 + r;
            float v[4];
            float vmax = -3.4e38f;
#pragma unroll
            for (int j = 0; j < 4; ++j) {
                v[j] = (float)acc[i][j][r] * SCLOGIT;
                vmax = fmaxf(vmax, v[j]);
            }
#pragma unroll
            for (int msk = 1; msk < 16; msk <<= 1)
                vmax = fmaxf(vmax, __shfl_xor(vmax, msk, 64));
            const float thr = vmax - MARGIN;
            int base = 0;
#pragma unroll
            for (int j = 0; j < 4; ++j) {
                const bool pred = v[j] > thr;
                const unsigned long long m = __ballot(pred) & grp;
                if (pred) {
                    const int pos = base + __popcll(m & low);
                    if (pos < KC)
                        cand[((size_t)row * 64 + wslot) * KC + pos] =
                            make_int2(n0 + wn * 64 + j * 16 + lc,
                                      __float_as_int(v[j]));
                }
                base += __popcll(m);
            }
            if (lc == 0) {
                tmax[(size_t)row * 64 + wslot] = vmax;
                cnts[(size_t)row * 64 + wslot] = base < KC ? base : KC;
            }
        }
}

// ---------------------------------------------------------------------------
// Final: global row max, filter candidates, then ONE-PASS per-wave online
// softmax-blend: each wave handles candidates c = wave, wave+4, ...; after
// the dot-product reduction the X row is already in registers, so the wave
// accumulates o += w_c * x immediately (X read ONCE, not twice), maintaining
// running (m, s) with rescale-on-new-max. Cross-wave LSE merge via LDS.
// 1 block/row, 256 threads.
// ---------------------------------------------------------------------------
__global__ __launch_bounds__(256) void sparse_out(const float* __restrict__ tmax,
                                                  const int* __restrict__ cnts,
                                                  const int2* __restrict__ cand,
                                                  const float* __restrict__ Qf,
                                                  const float* __restrict__ X,
                                                  float* __restrict__ out) {
    const int t = threadIdx.x;
    const int lane = t & 63, wave = t >> 6;
    const int row = blockIdx.x;

    __shared__ float gmax_s;
    __shared__ int   n2;
    __shared__ int   list[CAP];
    __shared__ float om[4], os[4];
    __shared__ __align__(16) float obuf[4][EMBED];   // 16 KB
    if (t == 0) n2 = 0;

    // global row max over 64 tile maxima (wave 0)
    float gm = -3.4e38f;
    if (t < 64) gm = tmax[(size_t)row * 64 + t];
#pragma unroll
    for (int off = 32; off >= 1; off >>= 1) gm = fmaxf(gm, __shfl_xor(gm, off, 64));
    if (t == 0) gmax_s = gm;
    __syncthreads();
    const float thr = gmax_s - MARGIN;

    // filter stored candidates (64 slots x KC entries)
    for (int e = t; e < 64 * KC; e += 256) {
        const int s = e >> 3, k = e & (KC - 1);
        if (k < cnts[(size_t)row * 64 + s]) {
            const int2 c = cand[((size_t)row * 64 + s) * KC + k];
            if (__int_as_float(c.y) > thr) {
                const int p = atomicAdd(&n2, 1);   // LDS atomic
                if (p < CAP) list[p] = c.x;
            }
        }
    }
    __syncthreads();
    const int nc = min(n2, CAP);

    // one-pass online softmax-blend, candidate c handled by wave (c & 3)
    float4 q[4];
#pragma unroll
    for (int i = 0; i < 4; ++i)
        q[i] = *(const float4*)&Qf[(size_t)row * EMBED + lane * 16 + i * 4];

    float m_w = -3.4e38f, s_w = 0.f;
    float4 o[4];
#pragma unroll
    for (int i = 0; i < 4; ++i) o[i] = make_float4(0.f, 0.f, 0.f, 0.f);

    for (int c = wave; c < nc; c += 4) {
        const float* xp = &X[(size_t)list[c] * EMBED + lane * 16];
        float4 x[4];
#pragma unroll
        for (int i = 0; i < 4; ++i) x[i] = *(const float4*)(xp + i * 4);
        float p = 0.f;
#pragma unroll
        for (int i = 0; i < 4; ++i)
            p += q[i].x * x[i].x + q[i].y * x[i].y + q[i].z * x[i].z + q[i].w * x[i].w;
#pragma unroll
        for (int off = 32; off >= 1; off >>= 1) p += __shfl_xor(p, off, 64);
        p *= 0.03125f;                       // all lanes hold the full logit

        if (p > m_w) {                       // rescale running state
            const float r = __expf(m_w - p); // first hit: exp(-inf) = 0
            s_w *= r;
#pragma unroll
            for (int i = 0; i < 4; ++i) {
                o[i].x *= r; o[i].y *= r; o[i].z *= r; o[i].w *= r;
            }
            m_w = p;
        }
        const float w = __expf(p - m_w);
        s_w += w;
#pragma unroll
        for (int i = 0; i < 4; ++i) {
            o[i].x += w * x[i].x; o[i].y += w * x[i].y;
            o[i].z += w * x[i].z; o[i].w += w * x[i].w;
        }
    }

    // publish per-wave partials
#pragma unroll
    for (int i = 0; i < 4; ++i)
        *(float4*)&obuf[wave][lane * 16 + i * 4] = o[i];
    if (lane == 0) { om[wave] = m_w; os[wave] = s_w; }
    __syncthreads();

    // cross-wave LSE merge; thread t owns output cols t*4..t*4+3
    const float m01 = fmaxf(om[0], om[1]), m23 = fmaxf(om[2], om[3]);
    const float m = fmaxf(m01, m23);
    float r0 = __expf(om[0] - m), r1 = __expf(om[1] - m);
    float r2 = __expf(om[2] - m), r3 = __expf(om[3] - m);
    const float Z = r0 * os[0] + r1 * os[1] + r2 * os[2] + r3 * os[3];
    const float inv = 1.0f / Z;
    const float4 a0 = *(const float4*)&obuf[0][t * 4];
    const float4 a1 = *(const float4*)&obuf[1][t * 4];
    const float4 a2 = *(const float4*)&obuf[2][t * 4];
    const float4 a3 = *(const float4*)&obuf[3][t * 4];
    float4 res;
    res.x = (r0 * a0.x + r1 * a1.x + r2 * a2.x + r3 * a3.x) * inv;
    res.y = (r0 * a0.y + r1 * a1.y + r2 * a2.y + r3 * a3.y) * inv;
    res.z = (r0 * a0.z + r1 * a1.z + r2 * a2.z + r3 * a3.z) * inv;
    res.w = (r0 * a0.w + r1 * a1.w + r2 * a2.w + r3 * a3.w) * inv;
    *(float4*)&out[(size_t)row * EMBED + t * 4] = res;
}

extern "C" void kernel_launch(void* const* d_in, const int* in_sizes, int n_in,
                              void* d_out, int out_size, void* d_ws, size_t ws_size,
                              hipStream_t stream) {
    const float* X  = (const float*)d_in[0];  // [4096,1024]
    const float* Wq = (const float*)d_in[1];  // [1024,1024]
    const float* Wk = (const float*)d_in[2];  // [1024,1024]
    float* out = (float*)d_out;

    char* ws = (char*)d_ws;
    const size_t MB = 1024 * 1024;
    unsigned short* Xhi = (unsigned short*)(ws + 0 * MB);   // 8 MB
    unsigned short* Xlo = (unsigned short*)(ws + 8 * MB);   // 8 MB
    signed char*    Xi8 = (signed char*)(ws + 16 * MB);     // 4 MB
    float*          Qf  = (float*)(ws + 20 * MB);           // 16 MB
    signed char*    Qi8 = (signed char*)(ws + 36 * MB);     // 4 MB
    float* tmax = (float*)(ws + 40 * MB);                   // 1 MB
    int*   cnts = (int*)(ws + 41 * MB);                     // 1 MB
    int2*  cand = (int2*)(ws + 42 * MB);                    // 16 MB
    unsigned short* Wqhi = (unsigned short*)(ws + 58 * MB);
    unsigned short* Wqlo = (unsigned short*)(ws + 60 * MB);
    unsigned short* Wkhi = (unsigned short*)(ws + 62 * MB);
    unsigned short* Wklo = (unsigned short*)(ws + 64 * MB);
    unsigned short* Thi  = (unsigned short*)(ws + 66 * MB);
    unsigned short* Tlo  = (unsigned short*)(ws + 68 * MB);
    // T fp32 partials (4 x 4 MB) alias the cand region: written/consumed
    // (t_fused -> t_merge) strictly before gemm_i8_scores writes cand.
    float* Tpart = (float*)(ws + 42 * MB);                  // 16 MB

    // 1) W splits only (the T GEMM's operands)
    prep_w<<<2048, 256, 0, stream>>>(
        (const float4*)Wq, (const float4*)Wk,
        (ushort4*)Wqhi, (ushort4*)Wqlo, (ushort4*)Wkhi, (ushort4*)Wklo);

    // 2) fused: split-K=4 T-partials (z<4) + X split (z>=4, overlapped)
    t_fused<<<dim3(16, 16, 20), 256, 0, stream>>>(
        Wkhi, Wklo, Wqhi, Wqlo, Tpart,
        (const float4*)X, (ushort4*)Xhi, (ushort4*)Xlo, (char4*)Xi8);

    // 3) merge partials -> split bf16 T
    t_merge<<<1024, 256, 0, stream>>>((const float4*)Tpart,
                                      (ushort4*)Thi, (ushort4*)Tlo);

    // 4) Qf = X @ T^T (= X @ M): all-bf16 global_load_lds, 8 waves, 48 KB
    qf_gemm<<<dim3(16, 32), 512, 0, stream>>>(
        Xhi, Xlo, Thi, Tlo, Qf, Qi8);

    // 5) i8 cheap scores (256x128 tile, m97 2-barrier, K-step 128)
    gemm_i8_scores<<<dim3(32, 16), 512, 0, stream>>>(Qi8, Xi8, tmax, cnts, cand);

    // 6) exact sparse softmax + gather (one-pass online softmax-blend)
    sparse_out<<<NTOK, 256, 0, stream>>>(tmax, cnts, cand, Qf, X, out);
}

// Round 8
// 168.676 us; speedup vs baseline: 1.0468x; 1.0468x over previous
//
#include <hip/hip_runtime.h>

#define EMBED 1024
#define NTOK  4096
#define MARGIN 256.0f   // i8 cheap-logit error sigma ~22; 2*5.5sigma + window
#define KC     8        // candidate slots per (row, wave-tile)
#define CAP    128      // final per-row candidate cap

// i8 scales: Xi8 = round(X * 127/5), Qi8 = round(Q' * 127/8192)
#define SX_INV 25.4f
#define SQ_INV 0.0155029296875f
#define SCLOGIT 0.07936198f   // (8192/127)*(5/127)/32

typedef short  s16x8 __attribute__((ext_vector_type(8)));
typedef float  f32x4 __attribute__((ext_vector_type(4)));
typedef int    i32x4 __attribute__((ext_vector_type(4)));

// ---- bf16 helpers (RNE) ----------------------------------------------------
__device__ __forceinline__ unsigned short f2bf(float f) {
    unsigned int u = __float_as_uint(f);
    u = (u + 0x7FFFu + ((u >> 16) & 1u)) >> 16;
    return (unsigned short)u;
}
__device__ __forceinline__ float bf2f(unsigned short h) {
    return __uint_as_float(((unsigned int)h) << 16);
}

// ---- async 16B global->LDS -------------------------------------------------
__device__ __forceinline__ void async16(const void* g, void* l) {
    __builtin_amdgcn_global_load_lds(
        (const __attribute__((address_space(1))) unsigned int*)g,
        (__attribute__((address_space(3))) unsigned int*)l, 16, 0, 0);
}

// Stage ROWS x 64-byte rows (row-major, swizzled 16B chunks) into LDS.
// ld in BYTES. 4-wave (256-thread) version.
template<int ROWS>
__device__ __forceinline__ void stage_rows(const char* __restrict__ g,
                                           int ld, char* lds, int wave, int lane) {
#pragma unroll
    for (int r = 0; r < ROWS / 64; ++r) {
        const int row0 = (wave * (ROWS / 64) + r) * 16;   // wave-uniform
        const int r_loc = lane >> 2;
        const int kc = (lane - (lane >> 3)) & 3;          // (slot - r_loc/2) & 3
        const char* gp = g + (size_t)(row0 + r_loc) * ld + kc * 16;
        char* lp = lds + row0 * 64;                       // wave-uniform base
        async16(gp, lp);
    }
}

// 8-wave (512-thread) version. ROWS must be a multiple of 128.
template<int ROWS>
__device__ __forceinline__ void stage_rows8(const char* __restrict__ g,
                                            int ld, char* lds, int wave, int lane) {
#pragma unroll
    for (int r = 0; r < ROWS / 128; ++r) {
        const int row0 = (wave * (ROWS / 128) + r) * 16;  // wave-uniform
        const int r_loc = lane >> 2;
        const int kc = (lane - (lane >> 3)) & 3;
        const char* gp = g + (size_t)(row0 + r_loc) * ld + kc * 16;
        char* lp = lds + row0 * 64;                       // wave-uniform base
        async16(gp, lp);
    }
}

__device__ __forceinline__ int frag_slot(int row, int kc) {
    return (kc + ((row & 15) >> 1)) & 3;
}
__device__ __forceinline__ s16x8 frag_bf16(const char* lds, int row, int kc) {
    return *(const s16x8*)(lds + row * 64 + frag_slot(row, kc) * 16);
}
__device__ __forceinline__ i32x4 frag_i8(const char* lds, int row, int kc) {
    return *(const i32x4*)(lds + row * 64 + frag_slot(row, kc) * 16);
}

// convert 8 fp32 -> bf16 hi/lo and store 16B each to LDS
__device__ __forceinline__ void cvt8_write(float4 a, float4 b, char* hw, char* lw) {
    float fs[8] = {a.x, a.y, a.z, a.w, b.x, b.y, b.z, b.w};
    s16x8 hv, lv;
#pragma unroll
    for (int e = 0; e < 8; ++e) {
        const unsigned short h = f2bf(fs[e]);
        hv[e] = (short)h;
        lv[e] = (short)f2bf(fs[e] - bf2f(h));
    }
    *(s16x8*)hw = hv;
    *(s16x8*)lw = lv;
}

// ---------------------------------------------------------------------------
// Fused dispatch: split-K=4 T-partial GEMM (z<4) + X split (z>=4).
// T = Wk @ Wq^T, 3-pass split bf16, 64x64 tile, K-slice = 256 per z.
// W operands are read as fp32 and split to bf16 hi/lo IN-KERNEL (reg-staged
// cvt + ds_write): prep_w is deleted. The T GEMM is latency-bound with idle
// VALU (R1: MfmaUtil 23%, VALUBusy 17%), so the cvt hides; read bytes are
// unchanged (4B fp32 = 2+2B hi/lo). X-split blocks (BW-bound) overlap the
// GEMM blocks (m114 co-scheduling). grid (16,16,20), 256 threads.
// ---------------------------------------------------------------------------
__global__ __launch_bounds__(256) void t_fused(
        const float* __restrict__ Wk,   // A source: T = Wk @ Wq^T
        const float* __restrict__ Wq,   // B source
        float* __restrict__ Cpart,
        const float4* __restrict__ X, ushort4* __restrict__ Xhi,
        ushort4* __restrict__ Xlo, char4* __restrict__ Xi8)
{
    constexpr int BM = 64, BN = 64, NCH = 2;
    __shared__ __align__(16) char As_hi[BM * 64 * NCH];
    __shared__ __align__(16) char Bs_hi[BN * 64 * NCH];
    __shared__ __align__(16) char As_lo[BM * 64 * NCH];
    __shared__ __align__(16) char Bs_lo[BN * 64 * NCH];

    const int t = threadIdx.x;
    const int z = blockIdx.z;

    if (z >= 4) {
        // ---- X split branch: 4096 blocks x 256 threads, 1 float4 each ----
        const int idx = (((z - 4) * 256) + blockIdx.y * 16 + blockIdx.x) * 256 + t;
        const float4 v = X[idx];
        ushort4 h, l;
        h.x = f2bf(v.x); l.x = f2bf(v.x - bf2f(h.x));
        h.y = f2bf(v.y); l.y = f2bf(v.y - bf2f(h.y));
        h.z = f2bf(v.z); l.z = f2bf(v.z - bf2f(h.z));
        h.w = f2bf(v.w); l.w = f2bf(v.w - bf2f(h.w));
        Xhi[idx] = h; Xlo[idx] = l;
        char4 c;
        c.x = (signed char)(int)rintf(fminf(fmaxf(v.x * SX_INV, -127.f), 127.f));
        c.y = (signed char)(int)rintf(fminf(fmaxf(v.y * SX_INV, -127.f), 127.f));
        c.z = (signed char)(int)rintf(fminf(fmaxf(v.z * SX_INV, -127.f), 127.f));
        c.w = (signed char)(int)rintf(fminf(fmaxf(v.w * SX_INV, -127.f), 127.f));
        Xi8[idx] = c;
        return;
    }

    // ---- T-partial GEMM branch: K in [z*256, z*256+256) ----
    const int lane = t & 63, wave = t >> 6;
    const int wm = wave >> 1, wn = wave & 1;
    const int m0 = blockIdx.y * BM, n0 = blockIdx.x * BN;

    f32x4 acc[2][2];
#pragma unroll
    for (int i = 0; i < 2; ++i)
#pragma unroll
        for (int j = 0; j < 2; ++j)
#pragma unroll
            for (int r = 0; r < 4; ++r) acc[i][j][r] = 0.f;

    // W staging: thread -> one row/slot; 8 fp32 -> bf16 hi/lo per chunk.
    const int srow = t >> 2, sslot = t & 3;               // 64 rows x 4 slots
    const float* aw = Wk + (size_t)(m0 + srow) * EMBED + sslot * 8;
    const float* bw = Wq + (size_t)(n0 + srow) * EMBED + sslot * 8;
    char* a_hi_w = As_hi + srow * 64 + frag_slot(srow, sslot) * 16;
    char* a_lo_w = As_lo + srow * 64 + frag_slot(srow, sslot) * 16;
    char* b_hi_w = Bs_hi + srow * 64 + frag_slot(srow, sslot) * 16;
    char* b_lo_w = Bs_lo + srow * 64 + frag_slot(srow, sslot) * 16;

    const int kc = lane >> 4;
    const int rr = lane & 15;
    const int kbeg = z * 256;

    for (int k0 = kbeg; k0 < kbeg + 256; k0 += 32 * NCH) {
        // issue all global loads first (latency overlap), then cvt+ds_write
        float4 fa[NCH][2], fb[NCH][2];
#pragma unroll
        for (int c = 0; c < NCH; ++c) {
            fa[c][0] = *(const float4*)(aw + k0 + c * 32);
            fa[c][1] = *(const float4*)(aw + k0 + c * 32 + 4);
            fb[c][0] = *(const float4*)(bw + k0 + c * 32);
            fb[c][1] = *(const float4*)(bw + k0 + c * 32 + 4);
        }
#pragma unroll
        for (int c = 0; c < NCH; ++c) {
            cvt8_write(fa[c][0], fa[c][1], a_hi_w + c * BM * 64, a_lo_w + c * BM * 64);
            cvt8_write(fb[c][0], fb[c][1], b_hi_w + c * BN * 64, b_lo_w + c * BN * 64);
        }
        __syncthreads();

#pragma unroll
        for (int c = 0; c < NCH; ++c) {
            s16x8 ah[2], bh[2], al[2], bl[2];
#pragma unroll
            for (int i = 0; i < 2; ++i)
                ah[i] = frag_bf16(As_hi + c * BM * 64, wm * 32 + i * 16 + rr, kc);
#pragma unroll
            for (int j = 0; j < 2; ++j)
                bh[j] = frag_bf16(Bs_hi + c * BN * 64, wn * 32 + j * 16 + rr, kc);
#pragma unroll
            for (int i = 0; i < 2; ++i)
                al[i] = frag_bf16(As_lo + c * BM * 64, wm * 32 + i * 16 + rr, kc);
#pragma unroll
            for (int j = 0; j < 2; ++j)
                bl[j] = frag_bf16(Bs_lo + c * BN * 64, wn * 32 + j * 16 + rr, kc);

#pragma unroll
            for (int i = 0; i < 2; ++i)
#pragma unroll
                for (int j = 0; j < 2; ++j)
                    acc[i][j] = __builtin_amdgcn_mfma_f32_16x16x32_bf16(ah[i], bh[j], acc[i][j], 0, 0, 0);
#pragma unroll
            for (int i = 0; i < 2; ++i)
#pragma unroll
                for (int j = 0; j < 2; ++j)
                    acc[i][j] = __builtin_amdgcn_mfma_f32_16x16x32_bf16(ah[i], bl[j], acc[i][j], 0, 0, 0);
#pragma unroll
            for (int i = 0; i < 2; ++i)
#pragma unroll
                for (int j = 0; j < 2; ++j)
                    acc[i][j] = __builtin_amdgcn_mfma_f32_16x16x32_bf16(al[i], bh[j], acc[i][j], 0, 0, 0);
        }
        __syncthreads();   // readers done before next iter's ds_writes
    }

    // fp32 partial epilogue into slice z
    const int lr = lane >> 4;
    const int lc = lane & 15;
    float* Cz = Cpart + (size_t)z * EMBED * EMBED;
#pragma unroll
    for (int i = 0; i < 2; ++i)
#pragma unroll
        for (int j = 0; j < 2; ++j)
#pragma unroll
            for (int r = 0; r < 4; ++r) {
                const int row = m0 + wm * 32 + i * 16 + lr * 4 + r;
                const int col = n0 + wn * 32 + j * 16 + lc;
                Cz[(size_t)row * EMBED + col] = acc[i][j][r];
            }
}

// ---------------------------------------------------------------------------
// Merge 4 fp32 T-partials -> split bf16 (Thi, Tlo). 1024 blocks x 256 thr.
// ---------------------------------------------------------------------------
__global__ __launch_bounds__(256) void t_merge(const float4* __restrict__ P,
                                               ushort4* __restrict__ Thi,
                                               ushort4* __restrict__ Tlo) {
    const int idx = blockIdx.x * 256 + threadIdx.x;   // over EMBED*EMBED/4
    const int S = EMBED * EMBED / 4;
    const float4 a = P[idx], b = P[idx + S], c = P[idx + 2 * S], d = P[idx + 3 * S];
    float4 s;
    s.x = (a.x + b.x) + (c.x + d.x);
    s.y = (a.y + b.y) + (c.y + d.y);
    s.z = (a.z + b.z) + (c.z + d.z);
    s.w = (a.w + b.w) + (c.w + d.w);
    ushort4 h, l;
    h.x = f2bf(s.x); l.x = f2bf(s.x - bf2f(h.x));
    h.y = f2bf(s.y); l.y = f2bf(s.y - bf2f(h.y));
    h.z = f2bf(s.z); l.z = f2bf(s.z - bf2f(h.z));
    h.w = f2bf(s.w); l.w = f2bf(s.w - bf2f(h.w));
    Thi[idx] = h; Tlo[idx] = l;
}

// ---------------------------------------------------------------------------
// Qf GEMM: Qf[4096,1024] = X[4096,1024] @ T^T, 3-pass split bf16 (hh+hl+lh).
// ALL operands bf16 in memory, staged via global_load_lds — zero cvt VALU.
// m97-style 2-barrier loop. 512 threads / 8 waves, per-wave 32x32 tile,
// LDS 48 KB. XCD-aware bijective swizzle. Epilogue: fp32 Qf + i8 Qi8.
// (R5 config — measured best.)
// ---------------------------------------------------------------------------
__global__ __launch_bounds__(512) void qf_gemm(
        const unsigned short* __restrict__ Ahi, const unsigned short* __restrict__ Alo,
        const unsigned short* __restrict__ Bhi, const unsigned short* __restrict__ Blo,
        float* __restrict__ C, signed char* __restrict__ Ci8)
{
    constexpr int BM = 128, BN = 64, NCH = 2;             // K-step = 64
    __shared__ __align__(16) char As_hi[BM * 64 * NCH];   // 16 KB
    __shared__ __align__(16) char As_lo[BM * 64 * NCH];   // 16 KB
    __shared__ __align__(16) char Bs_hi[BN * 64 * NCH];   // 8 KB
    __shared__ __align__(16) char Bs_lo[BN * 64 * NCH];   // 8 KB

    const int t = threadIdx.x;
    const int lane = t & 63, wave = t >> 6;
    const int wm = wave >> 1, wn = wave & 1;              // 4x2 wave grid

    // XCD swizzle: 512 blocks = 8 XCD x 64; per XCD 4 m-panels x 16 n-tiles
    const int bid = blockIdx.y * 16 + blockIdx.x;
    const int g = bid & 7, ii = bid >> 3;                 // ii in 0..63
    const int m0 = (g * 4 + (ii >> 4)) * BM;
    const int n0 = (ii & 15) * BN;

    f32x4 acc[2][2];
#pragma unroll
    for (int i = 0; i < 2; ++i)
#pragma unroll
        for (int j = 0; j < 2; ++j)
#pragma unroll
            for (int r = 0; r < 4; ++r) acc[i][j][r] = 0.f;

    const char* ah_g = (const char*)(Ahi + (size_t)m0 * EMBED);
    const char* al_g = (const char*)(Alo + (size_t)m0 * EMBED);

    // B staging: waves 0-3 stage Bs_hi, waves 4-7 stage Bs_lo (16 rows each)
    const unsigned short* bsrc = (wave < 4) ? Bhi : Blo;
    char* bdst = (wave < 4) ? Bs_hi : Bs_lo;
    const int w4 = wave & 3;
    const int brow0 = w4 * 16;
    const int b_rloc = lane >> 2;
    const int b_kc = (lane - (lane >> 3)) & 3;
    const char* bg = (const char*)(bsrc + (size_t)(n0 + brow0 + b_rloc) * EMBED) + b_kc * 16;
    char* b_lds = bdst + brow0 * 64;                      // wave-uniform

    const int kc = lane >> 4;
    const int rr = lane & 15;

    for (int k0 = 0; k0 < EMBED; k0 += 32 * NCH) {
#pragma unroll
        for (int c = 0; c < NCH; ++c) {
            const int kb = (k0 + 32 * c) * 2;
            stage_rows8<BM>(ah_g + kb, EMBED * 2, As_hi + c * BM * 64, wave, lane);
            stage_rows8<BM>(al_g + kb, EMBED * 2, As_lo + c * BM * 64, wave, lane);
            async16(bg + kb, b_lds + c * BN * 64);
        }
        __syncthreads();

#pragma unroll
        for (int c = 0; c < NCH; ++c) {
            s16x8 ah[2], bh[2], al[2], bl[2];
#pragma unroll
            for (int i = 0; i < 2; ++i)
                ah[i] = frag_bf16(As_hi + c * BM * 64, wm * 32 + i * 16 + rr, kc);
#pragma unroll
            for (int j = 0; j < 2; ++j)
                bh[j] = frag_bf16(Bs_hi + c * BN * 64, wn * 32 + j * 16 + rr, kc);
#pragma unroll
            for (int i = 0; i < 2; ++i)
                al[i] = frag_bf16(As_lo + c * BM * 64, wm * 32 + i * 16 + rr, kc);
#pragma unroll
            for (int j = 0; j < 2; ++j)
                bl[j] = frag_bf16(Bs_lo + c * BN * 64, wn * 32 + j * 16 + rr, kc);

#pragma unroll
            for (int i = 0; i < 2; ++i)
#pragma unroll
                for (int j = 0; j < 2; ++j)
                    acc[i][j] = __builtin_amdgcn_mfma_f32_16x16x32_bf16(ah[i], bh[j], acc[i][j], 0, 0, 0);
#pragma unroll
            for (int i = 0; i < 2; ++i)
#pragma unroll
                for (int j = 0; j < 2; ++j)
                    acc[i][j] = __builtin_amdgcn_mfma_f32_16x16x32_bf16(ah[i], bl[j], acc[i][j], 0, 0, 0);
#pragma unroll
            for (int i = 0; i < 2; ++i)
#pragma unroll
                for (int j = 0; j < 2; ++j)
                    acc[i][j] = __builtin_amdgcn_mfma_f32_16x16x32_bf16(al[i], bh[j], acc[i][j], 0, 0, 0);
        }
        __syncthreads();
    }

    // Epilogue: C/D layout col=lane&15, row=(lane>>4)*4+reg
    const int lr = lane >> 4;
    const int lc = lane & 15;
#pragma unroll
    for (int i = 0; i < 2; ++i)
#pragma unroll
        for (int j = 0; j < 2; ++j)
#pragma unroll
            for (int r = 0; r < 4; ++r) {
                const int row = m0 + wm * 32 + i * 16 + lr * 4 + r;
                const int col = n0 + wn * 32 + j * 16 + lc;
                const float v = acc[i][j][r];
                const size_t idx = (size_t)row * EMBED + col;
                C[idx] = v;
                const float q = fminf(fmaxf(v * SQ_INV, -127.f), 127.f);
                Ci8[idx] = (signed char)(int)rintf(q);
            }
}

// ---------------------------------------------------------------------------
// i8 scores GEMM + write-only candidate selection. m97 2-barrier loop,
// K-step 128. 256x128 tile, 512 threads / 8 waves, LDS 48 KB,
// 512 blocks fully co-resident. XCD swizzle: 8 XCD x (2 m-panels x 32 n).
// (R4/R5 config — measured stable.)
// ---------------------------------------------------------------------------
__global__ __launch_bounds__(512, 4) void gemm_i8_scores(
        const signed char* __restrict__ A,   // Qi8 [NTOK, EMBED]
        const signed char* __restrict__ B,   // Xi8 [NTOK, EMBED]
        float* __restrict__ tmax, int* __restrict__ cnts, int2* __restrict__ cand)
{
    __shared__ __align__(16) char As[256 * 64 * 2];   // 32 KB
    __shared__ __align__(16) char Bs[128 * 64 * 2];   // 16 KB

    const int t = threadIdx.x;
    const int lane = t & 63, wave = t >> 6;
    const int wm = wave >> 1, wn = wave & 1;          // 4x2 wave grid

    // XCD swizzle: 512 blocks = 8 XCD x 64; per XCD 2 m-panels x 32 n-tiles
    const int bid = blockIdx.y * 32 + blockIdx.x;
    const int g = bid & 7, ii = bid >> 3;             // ii in 0..63
    const int by = g * 2 + (ii >> 5);
    const int bx = ii & 31;
    const int m0 = by * 256, n0 = bx * 128;

    i32x4 acc[4][4];
#pragma unroll
    for (int i = 0; i < 4; ++i)
#pragma unroll
        for (int j = 0; j < 4; ++j)
#pragma unroll
            for (int r = 0; r < 4; ++r) acc[i][j][r] = 0;

    const char* a_g = (const char*)A + (size_t)m0 * EMBED;
    const char* b_g = (const char*)B + (size_t)n0 * EMBED;
    const int kc = lane >> 4;
    const int rr = lane & 15;

    for (int k0 = 0; k0 < EMBED; k0 += 128) {
#pragma unroll
        for (int c = 0; c < 2; ++c) {
            stage_rows8<256>(a_g + k0 + 64 * c, EMBED, As + c * 256 * 64, wave, lane);
            stage_rows8<128>(b_g + k0 + 64 * c, EMBED, Bs + c * 128 * 64, wave, lane);
        }
        __syncthreads();

#pragma unroll
        for (int c = 0; c < 2; ++c) {
            i32x4 af[4], bf[4];
#pragma unroll
            for (int i = 0; i < 4; ++i) af[i] = frag_i8(As + c * 256 * 64, wm * 64 + i * 16 + rr, kc);
#pragma unroll
            for (int j = 0; j < 4; ++j) bf[j] = frag_i8(Bs + c * 128 * 64, wn * 64 + j * 16 + rr, kc);
#pragma unroll
            for (int i = 0; i < 4; ++i)
#pragma unroll
                for (int j = 0; j < 4; ++j)
                    acc[i][j] = __builtin_amdgcn_mfma_i32_16x16x64_i8(af[i], bf[j], acc[i][j], 0, 0, 0);
        }
        __syncthreads();
    }

    // Write-only local selection epilogue (per-wave 64x64 — unchanged).
    const int lr = lane >> 4;
    const int lc = lane & 15;
    const int wslot = bx * 2 + wn;                    // 64 slots per row
    const unsigned long long grp = 0xFFFFull << (lr * 16);
    const unsigned long long low = (lane == 63) ? 0x7FFFFFFFFFFFFFFFull
                                                : ((1ull << lane) - 1);
#pragma unroll
    for (int i = 0; i < 4; ++i)
#pragma unroll
        for (int r = 0; r < 4; ++r) {
            const int row = m0 + wm * 64 + i * 16 + lr * 4 + r;
            float v[4];
            float vmax = -3.4e38f;
#pragma unroll
            for (int j = 0; j < 4; ++j) {
                v[j] = (float)acc[i][j][r] * SCLOGIT;
                vmax = fmaxf(vmax, v[j]);
            }
#pragma unroll
            for (int msk = 1; msk < 16; msk <<= 1)
                vmax = fmaxf(vmax, __shfl_xor(vmax, msk, 64));
            const float thr = vmax - MARGIN;
            int base = 0;
#pragma unroll
            for (int j = 0; j < 4; ++j) {
                const bool pred = v[j] > thr;
                const unsigned long long m = __ballot(pred) & grp;
                if (pred) {
                    const int pos = base + __popcll(m & low);
                    if (pos < KC)
                        cand[((size_t)row * 64 + wslot) * KC + pos] =
                            make_int2(n0 + wn * 64 + j * 16 + lc,
                                      __float_as_int(v[j]));
                }
                base += __popcll(m);
            }
            if (lc == 0) {
                tmax[(size_t)row * 64 + wslot] = vmax;
                cnts[(size_t)row * 64 + wslot] = base < KC ? base : KC;
            }
        }
}

// ---------------------------------------------------------------------------
// Final: global row max over 64 tile maxima, filter stored candidates,
// wave-parallel exact fp32 logits, softmax, blend fp32 X rows. 1 block/row.
// (R6 two-pass version — R7's one-pass online variant regressed −7.4 us:
// nc is tiny (~2-4), so the two simple pipelined passes beat the serial
// rescale chain + 16 KB LDS merge.)
// ---------------------------------------------------------------------------
__global__ __launch_bounds__(256) void sparse_out(const float* __restrict__ tmax,
                                                  const int* __restrict__ cnts,
                                                  const int2* __restrict__ cand,
                                                  const float* __restrict__ Qf,
                                                  const float* __restrict__ X,
                                                  float* __restrict__ out) {
    const int t = threadIdx.x;
    const int lane = t & 63, wave = t >> 6;
    const int row = blockIdx.x;

    __shared__ float gmax_s;
    __shared__ int   n2;
    __shared__ int   list[CAP];
    __shared__ float ll[CAP];
    if (t == 0) n2 = 0;

    // global row max over 64 tile maxima (wave 0)
    float gm = -3.4e38f;
    if (t < 64) gm = tmax[(size_t)row * 64 + t];
#pragma unroll
    for (int off = 32; off >= 1; off >>= 1) gm = fmaxf(gm, __shfl_xor(gm, off, 64));
    if (t == 0) gmax_s = gm;
    __syncthreads();
    const float thr = gmax_s - MARGIN;

    // filter stored candidates (64 slots x KC entries)
    for (int e = t; e < 64 * KC; e += 256) {
        const int s = e >> 3, k = e & (KC - 1);
        if (k < cnts[(size_t)row * 64 + s]) {
            const int2 c = cand[((size_t)row * 64 + s) * KC + k];
            if (__int_as_float(c.y) > thr) {
                const int p = atomicAdd(&n2, 1);   // LDS atomic
                if (p < CAP) list[p] = c.x;
            }
        }
    }
    __syncthreads();
    const int nc = min(n2, CAP);

    // exact logits, wave-parallel: candidate c handled by wave (c & 3)
    float4 q[4];
#pragma unroll
    for (int i = 0; i < 4; ++i)
        q[i] = *(const float4*)&Qf[(size_t)row * EMBED + lane * 16 + i * 4];
    for (int c = wave; c < nc; c += 4) {
        const float* xp = &X[(size_t)list[c] * EMBED + lane * 16];
        float p = 0.f;
#pragma unroll
        for (int i = 0; i < 4; ++i) {
            const float4 x4 = *(const float4*)(xp + i * 4);
            p += q[i].x * x4.x + q[i].y * x4.y + q[i].z * x4.z + q[i].w * x4.w;
        }
#pragma unroll
        for (int off = 32; off >= 1; off >>= 1) p += __shfl_xor(p, off, 64);
        if (lane == 0) ll[c] = p * 0.03125f;
    }
    __syncthreads();

    // exact softmax over candidates (redundant per thread; nc is tiny)
    float mt = -3.4e38f;
    for (int c = 0; c < nc; ++c) mt = fmaxf(mt, ll[c]);
    float wsum = 0.f;
    for (int c = 0; c < nc; ++c) wsum += __expf(ll[c] - mt);
    const float inv = 1.0f / wsum;

    float4 o = {0.f, 0.f, 0.f, 0.f};
    for (int c = 0; c < nc; ++c) {
        const float w = __expf(ll[c] - mt);
        const float4 xj = *(const float4*)&X[(size_t)list[c] * EMBED + t * 4];
        o.x += w * xj.x; o.y += w * xj.y; o.z += w * xj.z; o.w += w * xj.w;
    }
    o.x *= inv; o.y *= inv; o.z *= inv; o.w *= inv;
    *(float4*)&out[(size_t)row * EMBED + t * 4] = o;
}

extern "C" void kernel_launch(void* const* d_in, const int* in_sizes, int n_in,
                              void* d_out, int out_size, void* d_ws, size_t ws_size,
                              hipStream_t stream) {
    const float* X  = (const float*)d_in[0];  // [4096,1024]
    const float* Wq = (const float*)d_in[1];  // [1024,1024]
    const float* Wk = (const float*)d_in[2];  // [1024,1024]
    float* out = (float*)d_out;

    char* ws = (char*)d_ws;
    const size_t MB = 1024 * 1024;
    unsigned short* Xhi = (unsigned short*)(ws + 0 * MB);   // 8 MB
    unsigned short* Xlo = (unsigned short*)(ws + 8 * MB);   // 8 MB
    signed char*    Xi8 = (signed char*)(ws + 16 * MB);     // 4 MB
    float*          Qf  = (float*)(ws + 20 * MB);           // 16 MB
    signed char*    Qi8 = (signed char*)(ws + 36 * MB);     // 4 MB
    float* tmax = (float*)(ws + 40 * MB);                   // 1 MB
    int*   cnts = (int*)(ws + 41 * MB);                     // 1 MB
    int2*  cand = (int2*)(ws + 42 * MB);                    // 16 MB
    unsigned short* Thi  = (unsigned short*)(ws + 66 * MB);
    unsigned short* Tlo  = (unsigned short*)(ws + 68 * MB);
    // T fp32 partials (4 x 4 MB) alias the cand region: written/consumed
    // (t_fused -> t_merge) strictly before gemm_i8_scores writes cand.
    float* Tpart = (float*)(ws + 42 * MB);                  // 16 MB

    // 1) fused: split-K=4 T-partials with in-kernel W split (z<4)
    //    + X split (z>=4, overlapped). prep_w is gone.
    t_fused<<<dim3(16, 16, 20), 256, 0, stream>>>(
        Wk, Wq, Tpart,
        (const float4*)X, (ushort4*)Xhi, (ushort4*)Xlo, (char4*)Xi8);

    // 2) merge partials -> split bf16 T
    t_merge<<<1024, 256, 0, stream>>>((const float4*)Tpart,
                                      (ushort4*)Thi, (ushort4*)Tlo);

    // 3) Qf = X @ T^T (= X @ M): all-bf16 global_load_lds, 8 waves, 48 KB
    qf_gemm<<<dim3(16, 32), 512, 0, stream>>>(
        Xhi, Xlo, Thi, Tlo, Qf, Qi8);

    // 4) i8 cheap scores (256x128 tile, m97 2-barrier, K-step 128)
    gemm_i8_scores<<<dim3(32, 16), 512, 0, stream>>>(Qi8, Xi8, tmax, cnts, cand);

    // 5) exact sparse softmax + gather (two-pass, R6 version)
    sparse_out<<<NTOK, 256, 0, stream>>>(tmax, cnts, cand, Qf, X, out);
}

// Round 11
// 168.665 us; speedup vs baseline: 1.0469x; 1.0001x over previous
//
#include <hip/hip_runtime.h>

#define EMBED 1024
#define NTOK  4096
#define MARGIN 256.0f   // i8 cheap-logit error sigma ~22; 2*5.5sigma + window
#define KC     8        // candidate slots per (row, wave-tile)
#define CAP    128      // final per-row candidate cap

// i8 scales: Xi8 = round(X * 127/5), Qi8 = round(Q' * 127/8192)
#define SX_INV 25.4f
#define SQ_INV 0.0155029296875f
#define SCLOGIT 0.07936198f   // (8192/127)*(5/127)/32

typedef short  s16x8 __attribute__((ext_vector_type(8)));
typedef float  f32x4 __attribute__((ext_vector_type(4)));
typedef int    i32x4 __attribute__((ext_vector_type(4)));

// ---- bf16 helpers (RNE) ----------------------------------------------------
__device__ __forceinline__ unsigned short f2bf(float f) {
    unsigned int u = __float_as_uint(f);
    u = (u + 0x7FFFu + ((u >> 16) & 1u)) >> 16;
    return (unsigned short)u;
}
__device__ __forceinline__ float bf2f(unsigned short h) {
    return __uint_as_float(((unsigned int)h) << 16);
}

// ---- async 16B global->LDS -------------------------------------------------
__device__ __forceinline__ void async16(const void* g, void* l) {
    __builtin_amdgcn_global_load_lds(
        (const __attribute__((address_space(1))) unsigned int*)g,
        (__attribute__((address_space(3))) unsigned int*)l, 16, 0, 0);
}

// Stage ROWS x 64-byte rows (row-major, swizzled 16B chunks) into LDS.
// ld in BYTES. 4-wave (256-thread) version.
template<int ROWS>
__device__ __forceinline__ void stage_rows(const char* __restrict__ g,
                                           int ld, char* lds, int wave, int lane) {
#pragma unroll
    for (int r = 0; r < ROWS / 64; ++r) {
        const int row0 = (wave * (ROWS / 64) + r) * 16;   // wave-uniform
        const int r_loc = lane >> 2;
        const int kc = (lane - (lane >> 3)) & 3;          // (slot - r_loc/2) & 3
        const char* gp = g + (size_t)(row0 + r_loc) * ld + kc * 16;
        char* lp = lds + row0 * 64;                       // wave-uniform base
        async16(gp, lp);
    }
}

// 8-wave (512-thread) version. ROWS must be a multiple of 128.
template<int ROWS>
__device__ __forceinline__ void stage_rows8(const char* __restrict__ g,
                                            int ld, char* lds, int wave, int lane) {
#pragma unroll
    for (int r = 0; r < ROWS / 128; ++r) {
        const int row0 = (wave * (ROWS / 128) + r) * 16;  // wave-uniform
        const int r_loc = lane >> 2;
        const int kc = (lane - (lane >> 3)) & 3;
        const char* gp = g + (size_t)(row0 + r_loc) * ld + kc * 16;
        char* lp = lds + row0 * 64;                       // wave-uniform base
        async16(gp, lp);
    }
}

__device__ __forceinline__ int frag_slot(int row, int kc) {
    return (kc + ((row & 15) >> 1)) & 3;
}
__device__ __forceinline__ s16x8 frag_bf16(const char* lds, int row, int kc) {
    return *(const s16x8*)(lds + row * 64 + frag_slot(row, kc) * 16);
}
__device__ __forceinline__ i32x4 frag_i8(const char* lds, int row, int kc) {
    return *(const i32x4*)(lds + row * 64 + frag_slot(row, kc) * 16);
}

// convert 8 fp32 -> bf16 hi/lo and store 16B each to LDS
__device__ __forceinline__ void cvt8_write(float4 a, float4 b, char* hw, char* lw) {
    float fs[8] = {a.x, a.y, a.z, a.w, b.x, b.y, b.z, b.w};
    s16x8 hv, lv;
#pragma unroll
    for (int e = 0; e < 8; ++e) {
        const unsigned short h = f2bf(fs[e]);
        hv[e] = (short)h;
        lv[e] = (short)f2bf(fs[e] - bf2f(h));
    }
    *(s16x8*)hw = hv;
    *(s16x8*)lw = lv;
}

// ---------------------------------------------------------------------------
// Fused dispatch: split-K=4 T-partial GEMM (z<4) + X split (z>=4).
// T = Wk @ Wq^T, 3-pass split bf16, 64x64 tile, K-slice = 256 per z.
// W operands are read as fp32 and split to bf16 hi/lo IN-KERNEL (reg-staged
// cvt + ds_write). The T GEMM is latency-bound with idle VALU, so the cvt
// hides; read bytes unchanged. X-split blocks (BW-bound) overlap the GEMM
// blocks (m114 co-scheduling). grid (16,16,20), 256 threads. (R8 config.)
// ---------------------------------------------------------------------------
__global__ __launch_bounds__(256) void t_fused(
        const float* __restrict__ Wk,   // A source: T = Wk @ Wq^T
        const float* __restrict__ Wq,   // B source
        float* __restrict__ Cpart,
        const float4* __restrict__ X, ushort4* __restrict__ Xhi,
        ushort4* __restrict__ Xlo, char4* __restrict__ Xi8)
{
    constexpr int BM = 64, BN = 64, NCH = 2;
    __shared__ __align__(16) char As_hi[BM * 64 * NCH];
    __shared__ __align__(16) char Bs_hi[BN * 64 * NCH];
    __shared__ __align__(16) char As_lo[BM * 64 * NCH];
    __shared__ __align__(16) char Bs_lo[BN * 64 * NCH];

    const int t = threadIdx.x;
    const int z = blockIdx.z;

    if (z >= 4) {
        // ---- X split branch: 4096 blocks x 256 threads, 1 float4 each ----
        const int idx = (((z - 4) * 256) + blockIdx.y * 16 + blockIdx.x) * 256 + t;
        const float4 v = X[idx];
        ushort4 h, l;
        h.x = f2bf(v.x); l.x = f2bf(v.x - bf2f(h.x));
        h.y = f2bf(v.y); l.y = f2bf(v.y - bf2f(h.y));
        h.z = f2bf(v.z); l.z = f2bf(v.z - bf2f(h.z));
        h.w = f2bf(v.w); l.w = f2bf(v.w - bf2f(h.w));
        Xhi[idx] = h; Xlo[idx] = l;
        char4 c;
        c.x = (signed char)(int)rintf(fminf(fmaxf(v.x * SX_INV, -127.f), 127.f));
        c.y = (signed char)(int)rintf(fminf(fmaxf(v.y * SX_INV, -127.f), 127.f));
        c.z = (signed char)(int)rintf(fminf(fmaxf(v.z * SX_INV, -127.f), 127.f));
        c.w = (signed char)(int)rintf(fminf(fmaxf(v.w * SX_INV, -127.f), 127.f));
        Xi8[idx] = c;
        return;
    }

    // ---- T-partial GEMM branch: K in [z*256, z*256+256) ----
    const int lane = t & 63, wave = t >> 6;
    const int wm = wave >> 1, wn = wave & 1;
    const int m0 = blockIdx.y * BM, n0 = blockIdx.x * BN;

    f32x4 acc[2][2];
#pragma unroll
    for (int i = 0; i < 2; ++i)
#pragma unroll
        for (int j = 0; j < 2; ++j)
#pragma unroll
            for (int r = 0; r < 4; ++r) acc[i][j][r] = 0.f;

    // W staging: thread -> one row/slot; 8 fp32 -> bf16 hi/lo per chunk.
    const int srow = t >> 2, sslot = t & 3;               // 64 rows x 4 slots
    const float* aw = Wk + (size_t)(m0 + srow) * EMBED + sslot * 8;
    const float* bw = Wq + (size_t)(n0 + srow) * EMBED + sslot * 8;
    char* a_hi_w = As_hi + srow * 64 + frag_slot(srow, sslot) * 16;
    char* a_lo_w = As_lo + srow * 64 + frag_slot(srow, sslot) * 16;
    char* b_hi_w = Bs_hi + srow * 64 + frag_slot(srow, sslot) * 16;
    char* b_lo_w = Bs_lo + srow * 64 + frag_slot(srow, sslot) * 16;

    const int kc = lane >> 4;
    const int rr = lane & 15;
    const int kbeg = z * 256;

    for (int k0 = kbeg; k0 < kbeg + 256; k0 += 32 * NCH) {
        // issue all global loads first (latency overlap), then cvt+ds_write
        float4 fa[NCH][2], fb[NCH][2];
#pragma unroll
        for (int c = 0; c < NCH; ++c) {
            fa[c][0] = *(const float4*)(aw + k0 + c * 32);
            fa[c][1] = *(const float4*)(aw + k0 + c * 32 + 4);
            fb[c][0] = *(const float4*)(bw + k0 + c * 32);
            fb[c][1] = *(const float4*)(bw + k0 + c * 32 + 4);
        }
#pragma unroll
        for (int c = 0; c < NCH; ++c) {
            cvt8_write(fa[c][0], fa[c][1], a_hi_w + c * BM * 64, a_lo_w + c * BM * 64);
            cvt8_write(fb[c][0], fb[c][1], b_hi_w + c * BN * 64, b_lo_w + c * BN * 64);
        }
        __syncthreads();

#pragma unroll
        for (int c = 0; c < NCH; ++c) {
            s16x8 ah[2], bh[2], al[2], bl[2];
#pragma unroll
            for (int i = 0; i < 2; ++i)
                ah[i] = frag_bf16(As_hi + c * BM * 64, wm * 32 + i * 16 + rr, kc);
#pragma unroll
            for (int j = 0; j < 2; ++j)
                bh[j] = frag_bf16(Bs_hi + c * BN * 64, wn * 32 + j * 16 + rr, kc);
#pragma unroll
            for (int i = 0; i < 2; ++i)
                al[i] = frag_bf16(As_lo + c * BM * 64, wm * 32 + i * 16 + rr, kc);
#pragma unroll
            for (int j = 0; j < 2; ++j)
                bl[j] = frag_bf16(Bs_lo + c * BN * 64, wn * 32 + j * 16 + rr, kc);

#pragma unroll
            for (int i = 0; i < 2; ++i)
#pragma unroll
                for (int j = 0; j < 2; ++j)
                    acc[i][j] = __builtin_amdgcn_mfma_f32_16x16x32_bf16(ah[i], bh[j], acc[i][j], 0, 0, 0);
#pragma unroll
            for (int i = 0; i < 2; ++i)
#pragma unroll
                for (int j = 0; j < 2; ++j)
                    acc[i][j] = __builtin_amdgcn_mfma_f32_16x16x32_bf16(ah[i], bl[j], acc[i][j], 0, 0, 0);
#pragma unroll
            for (int i = 0; i < 2; ++i)
#pragma unroll
                for (int j = 0; j < 2; ++j)
                    acc[i][j] = __builtin_amdgcn_mfma_f32_16x16x32_bf16(al[i], bh[j], acc[i][j], 0, 0, 0);
        }
        __syncthreads();   // readers done before next iter's ds_writes
    }

    // fp32 partial epilogue into slice z
    const int lr = lane >> 4;
    const int lc = lane & 15;
    float* Cz = Cpart + (size_t)z * EMBED * EMBED;
#pragma unroll
    for (int i = 0; i < 2; ++i)
#pragma unroll
        for (int j = 0; j < 2; ++j)
#pragma unroll
            for (int r = 0; r < 4; ++r) {
                const int row = m0 + wm * 32 + i * 16 + lr * 4 + r;
                const int col = n0 + wn * 32 + j * 16 + lc;
                Cz[(size_t)row * EMBED + col] = acc[i][j][r];
            }
}

// ---------------------------------------------------------------------------
// Merge 4 fp32 T-partials -> split bf16 (Thi, Tlo). 1024 blocks x 256 thr.
// ---------------------------------------------------------------------------
__global__ __launch_bounds__(256) void t_merge(const float4* __restrict__ P,
                                               ushort4* __restrict__ Thi,
                                               ushort4* __restrict__ Tlo) {
    const int idx = blockIdx.x * 256 + threadIdx.x;   // over EMBED*EMBED/4
    const int S = EMBED * EMBED / 4;
    const float4 a = P[idx], b = P[idx + S], c = P[idx + 2 * S], d = P[idx + 3 * S];
    float4 s;
    s.x = (a.x + b.x) + (c.x + d.x);
    s.y = (a.y + b.y) + (c.y + d.y);
    s.z = (a.z + b.z) + (c.z + d.z);
    s.w = (a.w + b.w) + (c.w + d.w);
    ushort4 h, l;
    h.x = f2bf(s.x); l.x = f2bf(s.x - bf2f(h.x));
    h.y = f2bf(s.y); l.y = f2bf(s.y - bf2f(h.y));
    h.z = f2bf(s.z); l.z = f2bf(s.z - bf2f(h.z));
    h.w = f2bf(s.w); l.w = f2bf(s.w - bf2f(h.w));
    Thi[idx] = h; Tlo[idx] = l;
}

// ---------------------------------------------------------------------------
// Qf GEMM: Qf[4096,1024] = X[4096,1024] @ T^T, 3-pass split bf16 (hh+hl+lh).
// ALL operands bf16 in memory, staged via global_load_lds — zero cvt VALU.
// m97-style 2-barrier loop. 512 threads / 8 waves, per-wave 32x32 tile,
// LDS 48 KB. XCD-aware bijective swizzle. Epilogue: fp32 Qf + i8 Qi8.
// (R5 config — measured best.)
// ---------------------------------------------------------------------------
__global__ __launch_bounds__(512) void qf_gemm(
        const unsigned short* __restrict__ Ahi, const unsigned short* __restrict__ Alo,
        const unsigned short* __restrict__ Bhi, const unsigned short* __restrict__ Blo,
        float* __restrict__ C, signed char* __restrict__ Ci8)
{
    constexpr int BM = 128, BN = 64, NCH = 2;             // K-step = 64
    __shared__ __align__(16) char As_hi[BM * 64 * NCH];   // 16 KB
    __shared__ __align__(16) char As_lo[BM * 64 * NCH];   // 16 KB
    __shared__ __align__(16) char Bs_hi[BN * 64 * NCH];   // 8 KB
    __shared__ __align__(16) char Bs_lo[BN * 64 * NCH];   // 8 KB

    const int t = threadIdx.x;
    const int lane = t & 63, wave = t >> 6;
    const int wm = wave >> 1, wn = wave & 1;              // 4x2 wave grid

    // XCD swizzle: 512 blocks = 8 XCD x 64; per XCD 4 m-panels x 16 n-tiles
    const int bid = blockIdx.y * 16 + blockIdx.x;
    const int g = bid & 7, ii = bid >> 3;                 // ii in 0..63
    const int m0 = (g * 4 + (ii >> 4)) * BM;
    const int n0 = (ii & 15) * BN;

    f32x4 acc[2][2];
#pragma unroll
    for (int i = 0; i < 2; ++i)
#pragma unroll
        for (int j = 0; j < 2; ++j)
#pragma unroll
            for (int r = 0; r < 4; ++r) acc[i][j][r] = 0.f;

    const char* ah_g = (const char*)(Ahi + (size_t)m0 * EMBED);
    const char* al_g = (const char*)(Alo + (size_t)m0 * EMBED);

    // B staging: waves 0-3 stage Bs_hi, waves 4-7 stage Bs_lo (16 rows each)
    const unsigned short* bsrc = (wave < 4) ? Bhi : Blo;
    char* bdst = (wave < 4) ? Bs_hi : Bs_lo;
    const int w4 = wave & 3;
    const int brow0 = w4 * 16;
    const int b_rloc = lane >> 2;
    const int b_kc = (lane - (lane >> 3)) & 3;
    const char* bg = (const char*)(bsrc + (size_t)(n0 + brow0 + b_rloc) * EMBED) + b_kc * 16;
    char* b_lds = bdst + brow0 * 64;                      // wave-uniform

    const int kc = lane >> 4;
    const int rr = lane & 15;

    for (int k0 = 0; k0 < EMBED; k0 += 32 * NCH) {
#pragma unroll
        for (int c = 0; c < NCH; ++c) {
            const int kb = (k0 + 32 * c) * 2;
            stage_rows8<BM>(ah_g + kb, EMBED * 2, As_hi + c * BM * 64, wave, lane);
            stage_rows8<BM>(al_g + kb, EMBED * 2, As_lo + c * BM * 64, wave, lane);
            async16(bg + kb, b_lds + c * BN * 64);
        }
        __syncthreads();

#pragma unroll
        for (int c = 0; c < NCH; ++c) {
            s16x8 ah[2], bh[2], al[2], bl[2];
#pragma unroll
            for (int i = 0; i < 2; ++i)
                ah[i] = frag_bf16(As_hi + c * BM * 64, wm * 32 + i * 16 + rr, kc);
#pragma unroll
            for (int j = 0; j < 2; ++j)
                bh[j] = frag_bf16(Bs_hi + c * BN * 64, wn * 32 + j * 16 + rr, kc);
#pragma unroll
            for (int i = 0; i < 2; ++i)
                al[i] = frag_bf16(As_lo + c * BM * 64, wm * 32 + i * 16 + rr, kc);
#pragma unroll
            for (int j = 0; j < 2; ++j)
                bl[j] = frag_bf16(Bs_lo + c * BN * 64, wn * 32 + j * 16 + rr, kc);

#pragma unroll
            for (int i = 0; i < 2; ++i)
#pragma unroll
                for (int j = 0; j < 2; ++j)
                    acc[i][j] = __builtin_amdgcn_mfma_f32_16x16x32_bf16(ah[i], bh[j], acc[i][j], 0, 0, 0);
#pragma unroll
            for (int i = 0; i < 2; ++i)
#pragma unroll
                for (int j = 0; j < 2; ++j)
                    acc[i][j] = __builtin_amdgcn_mfma_f32_16x16x32_bf16(ah[i], bl[j], acc[i][j], 0, 0, 0);
#pragma unroll
            for (int i = 0; i < 2; ++i)
#pragma unroll
                for (int j = 0; j < 2; ++j)
                    acc[i][j] = __builtin_amdgcn_mfma_f32_16x16x32_bf16(al[i], bh[j], acc[i][j], 0, 0, 0);
        }
        __syncthreads();
    }

    // Epilogue: C/D layout col=lane&15, row=(lane>>4)*4+reg
    const int lr = lane >> 4;
    const int lc = lane & 15;
#pragma unroll
    for (int i = 0; i < 2; ++i)
#pragma unroll
        for (int j = 0; j < 2; ++j)
#pragma unroll
            for (int r = 0; r < 4; ++r) {
                const int row = m0 + wm * 32 + i * 16 + lr * 4 + r;
                const int col = n0 + wn * 32 + j * 16 + lc;
                const float v = acc[i][j][r];
                const size_t idx = (size_t)row * EMBED + col;
                C[idx] = v;
                const float q = fminf(fmaxf(v * SQ_INV, -127.f), 127.f);
                Ci8[idx] = (signed char)(int)rintf(q);
            }
}

// ---------------------------------------------------------------------------
// i8 scores GEMM + write-only candidate selection. m97 2-barrier loop,
// K-step 128. 256x128 tile, 512 threads / 8 waves, LDS 48 KB,
// 512 blocks fully co-resident. XCD swizzle: 8 XCD x (2 m-panels x 32 n).
// (R4-R8 config — measured stable. MFMA 16x16x64 i8 matches the epilogue.)
// ---------------------------------------------------------------------------
__global__ __launch_bounds__(512, 4) void gemm_i8_scores(
        const signed char* __restrict__ A,   // Qi8 [NTOK, EMBED]
        const signed char* __restrict__ B,   // Xi8 [NTOK, EMBED]
        float* __restrict__ tmax, int* __restrict__ cnts, int2* __restrict__ cand)
{
    __shared__ __align__(16) char As[256 * 64 * 2];   // 32 KB
    __shared__ __align__(16) char Bs[128 * 64 * 2];   // 16 KB

    const int t = threadIdx.x;
    const int lane = t & 63, wave = t >> 6;
    const int wm = wave >> 1, wn = wave & 1;          // 4x2 wave grid

    // XCD swizzle: 512 blocks = 8 XCD x 64; per XCD 2 m-panels x 32 n-tiles
    const int bid = blockIdx.y * 32 + blockIdx.x;
    const int g = bid & 7, ii = bid >> 3;             // ii in 0..63
    const int by = g * 2 + (ii >> 5);
    const int bx = ii & 31;
    const int m0 = by * 256, n0 = bx * 128;

    i32x4 acc[4][4];
#pragma unroll
    for (int i = 0; i < 4; ++i)
#pragma unroll
        for (int j = 0; j < 4; ++j)
#pragma unroll
            for (int r = 0; r < 4; ++r) acc[i][j][r] = 0;

    const char* a_g = (const char*)A + (size_t)m0 * EMBED;
    const char* b_g = (const char*)B + (size_t)n0 * EMBED;
    const int kc = lane >> 4;
    const int rr = lane & 15;

    for (int k0 = 0; k0 < EMBED; k0 += 128) {
#pragma unroll
        for (int c = 0; c < 2; ++c) {
            stage_rows8<256>(a_g + k0 + 64 * c, EMBED, As + c * 256 * 64, wave, lane);
            stage_rows8<128>(b_g + k0 + 64 * c, EMBED, Bs + c * 128 * 64, wave, lane);
        }
        __syncthreads();

#pragma unroll
        for (int c = 0; c < 2; ++c) {
            i32x4 af[4], bf[4];
#pragma unroll
            for (int i = 0; i < 4; ++i) af[i] = frag_i8(As + c * 256 * 64, wm * 64 + i * 16 + rr, kc);
#pragma unroll
            for (int j = 0; j < 4; ++j) bf[j] = frag_i8(Bs + c * 128 * 64, wn * 64 + j * 16 + rr, kc);
#pragma unroll
            for (int i = 0; i < 4; ++i)
#pragma unroll
                for (int j = 0; j < 4; ++j)
                    acc[i][j] = __builtin_amdgcn_mfma_i32_16x16x64_i8(af[i], bf[j], acc[i][j], 0, 0, 0);
        }
        __syncthreads();
    }

    // Write-only local selection epilogue (per-wave 64x64 — unchanged).
    const int lr = lane >> 4;
    const int lc = lane & 15;
    const int wslot = bx * 2 + wn;                    // 64 slots per row
    const unsigned long long grp = 0xFFFFull << (lr * 16);
    const unsigned long long low = (lane == 63) ? 0x7FFFFFFFFFFFFFFFull
                                                : ((1ull << lane) - 1);
#pragma unroll
    for (int i = 0; i < 4; ++i)
#pragma unroll
        for (int r = 0; r < 4; ++r) {
            const int row = m0 + wm * 64 + i * 16 + lr * 4 + r;
            float v[4];
            float vmax = -3.4e38f;
#pragma unroll
            for (int j = 0; j < 4; ++j) {
                v[j] = (float)acc[i][j][r] * SCLOGIT;
                vmax = fmaxf(vmax, v[j]);
            }
#pragma unroll
            for (int msk = 1; msk < 16; msk <<= 1)
                vmax = fmaxf(vmax, __shfl_xor(vmax, msk, 64));
            const float thr = vmax - MARGIN;
            int base = 0;
#pragma unroll
            for (int j = 0; j < 4; ++j) {
                const bool pred = v[j] > thr;
                const unsigned long long m = __ballot(pred) & grp;
                if (pred) {
                    const int pos = base + __popcll(m & low);
                    if (pos < KC)
                        cand[((size_t)row * 64 + wslot) * KC + pos] =
                            make_int2(n0 + wn * 64 + j * 16 + lc,
                                      __float_as_int(v[j]));
                }
                base += __popcll(m);
            }
            if (lc == 0) {
                tmax[(size_t)row * 64 + wslot] = vmax;
                cnts[(size_t)row * 64 + wslot] = base < KC ? base : KC;
            }
        }
}

// ---------------------------------------------------------------------------
// Final: global row max, filter candidates, wave-parallel exact logits,
// PARALLEL weight precompute (wave-0 mt reduce + one exp per thread into
// LDS), then blend with a block-uniform skip of negligible candidates
// (w < wsum*1e-7 -> contribution < 1e-6, 4 orders below tolerance).
// Cuts pass-2 X-row traffic to only the weighty candidates. 1 block/row.
// ---------------------------------------------------------------------------
__global__ __launch_bounds__(256) void sparse_out(const float* __restrict__ tmax,
                                                  const int* __restrict__ cnts,
                                                  const int2* __restrict__ cand,
                                                  const float* __restrict__ Qf,
                                                  const float* __restrict__ X,
                                                  float* __restrict__ out) {
    const int t = threadIdx.x;
    const int lane = t & 63, wave = t >> 6;
    const int row = blockIdx.x;

    __shared__ float gmax_s;
    __shared__ int   n2;
    __shared__ int   list[CAP];
    __shared__ float ll[CAP];
    __shared__ float wl[CAP];
    __shared__ float mt_s;
    if (t == 0) n2 = 0;

    // global row max over 64 tile maxima (wave 0)
    float gm = -3.4e38f;
    if (t < 64) gm = tmax[(size_t)row * 64 + t];
#pragma unroll
    for (int off = 32; off >= 1; off >>= 1) gm = fmaxf(gm, __shfl_xor(gm, off, 64));
    if (t == 0) gmax_s = gm;
    __syncthreads();
    const float thr = gmax_s - MARGIN;

    // filter stored candidates (64 slots x KC entries)
    for (int e = t; e < 64 * KC; e += 256) {
        const int s = e >> 3, k = e & (KC - 1);
        if (k < cnts[(size_t)row * 64 + s]) {
            const int2 c = cand[((size_t)row * 64 + s) * KC + k];
            if (__int_as_float(c.y) > thr) {
                const int p = atomicAdd(&n2, 1);   // LDS atomic
                if (p < CAP) list[p] = c.x;
            }
        }
    }
    __syncthreads();
    const int nc = min(n2, CAP);

    // exact logits, wave-parallel: candidate c handled by wave (c & 3)
    float4 q[4];
#pragma unroll
    for (int i = 0; i < 4; ++i)
        q[i] = *(const float4*)&Qf[(size_t)row * EMBED + lane * 16 + i * 4];
    for (int c = wave; c < nc; c += 4) {
        const float* xp = &X[(size_t)list[c] * EMBED + lane * 16];
        float p = 0.f;
#pragma unroll
        for (int i = 0; i < 4; ++i) {
            const float4 x4 = *(const float4*)(xp + i * 4);
            p += q[i].x * x4.x + q[i].y * x4.y + q[i].z * x4.z + q[i].w * x4.w;
        }
#pragma unroll
        for (int off = 32; off >= 1; off >>= 1) p += __shfl_xor(p, off, 64);
        if (lane == 0) ll[c] = p * 0.03125f;
    }
    __syncthreads();

    // mt = max logit (wave 0 reduce), then parallel weight fill
    if (t < 64) {
        float m = -3.4e38f;
        for (int c = t; c < nc; c += 64) m = fmaxf(m, ll[c]);
#pragma unroll
        for (int off = 32; off >= 1; off >>= 1) m = fmaxf(m, __shfl_xor(m, off, 64));
        if (t == 0) mt_s = m;
    }
    __syncthreads();
    const float mt = mt_s;
    if (t < CAP) wl[t] = (t < nc) ? __expf(ll[t] - mt) : 0.f;
    __syncthreads();

    // wsum from LDS (broadcast reads, no exp)
    float wsum = 0.f;
    for (int c = 0; c < nc; ++c) wsum += wl[c];
    const float inv = 1.0f / wsum;
    const float wthr = wsum * 1e-7f;     // uniform skip threshold

    float4 o = {0.f, 0.f, 0.f, 0.f};
    for (int c = 0; c < nc; ++c) {
        const float w = wl[c];
        if (w < wthr) continue;          // block-uniform branch (LDS value)
        const float4 xj = *(const float4*)&X[(size_t)list[c] * EMBED + t * 4];
        o.x += w * xj.x; o.y += w * xj.y; o.z += w * xj.z; o.w += w * xj.w;
    }
    o.x *= inv; o.y *= inv; o.z *= inv; o.w *= inv;
    *(float4*)&out[(size_t)row * EMBED + t * 4] = o;
}

extern "C" void kernel_launch(void* const* d_in, const int* in_sizes, int n_in,
                              void* d_out, int out_size, void* d_ws, size_t ws_size,
                              hipStream_t stream) {
    const float* X  = (const float*)d_in[0];  // [4096,1024]
    const float* Wq = (const float*)d_in[1];  // [1024,1024]
    const float* Wk = (const float*)d_in[2];  // [1024,1024]
    float* out = (float*)d_out;

    char* ws = (char*)d_ws;
    const size_t MB = 1024 * 1024;
    unsigned short* Xhi = (unsigned short*)(ws + 0 * MB);   // 8 MB
    unsigned short* Xlo = (unsigned short*)(ws + 8 * MB);   // 8 MB
    signed char*    Xi8 = (signed char*)(ws + 16 * MB);     // 4 MB
    float*          Qf  = (float*)(ws + 20 * MB);           // 16 MB
    signed char*    Qi8 = (signed char*)(ws + 36 * MB);     // 4 MB
    float* tmax = (float*)(ws + 40 * MB);                   // 1 MB
    int*   cnts = (int*)(ws + 41 * MB);                     // 1 MB
    int2*  cand = (int2*)(ws + 42 * MB);                    // 16 MB
    unsigned short* Thi  = (unsigned short*)(ws + 66 * MB);
    unsigned short* Tlo  = (unsigned short*)(ws + 68 * MB);
    // T fp32 partials (4 x 4 MB) alias the cand region: written/consumed
    // (t_fused -> t_merge) strictly before gemm_i8_scores writes cand.
    float* Tpart = (float*)(ws + 42 * MB);                  // 16 MB

    // 1) fused: split-K=4 T-partials with in-kernel W split (z<4)
    //    + X split (z>=4, overlapped)
    t_fused<<<dim3(16, 16, 20), 256, 0, stream>>>(
        Wk, Wq, Tpart,
        (const float4*)X, (ushort4*)Xhi, (ushort4*)Xlo, (char4*)Xi8);

    // 2) merge partials -> split bf16 T
    t_merge<<<1024, 256, 0, stream>>>((const float4*)Tpart,
                                      (ushort4*)Thi, (ushort4*)Tlo);

    // 3) Qf = X @ T^T (= X @ M): all-bf16 global_load_lds, 8 waves, 48 KB
    qf_gemm<<<dim3(16, 32), 512, 0, stream>>>(
        Xhi, Xlo, Thi, Tlo, Qf, Qi8);

    // 4) i8 cheap scores (256x128 tile, m97 2-barrier, K-step 128)
    gemm_i8_scores<<<dim3(32, 16), 512, 0, stream>>>(Qi8, Xi8, tmax, cnts, cand);

    // 5) exact sparse softmax + gather (two-pass + weight-skip blend)
    sparse_out<<<NTOK, 256, 0, stream>>>(tmax, cnts, cand, Qf, X, out);
}

// Round 12
// 167.720 us; speedup vs baseline: 1.0528x; 1.0056x over previous
//
#include <hip/hip_runtime.h>

#define EMBED 1024
#define NTOK  4096
#define MARGIN 256.0f   // i8 cheap-logit error sigma ~22; 2*5.5sigma + window
#define KC     8        // candidate slots per (row, wave-tile)
#define CAP    128      // final per-row candidate cap

// i8 scales: Xi8 = round(X * 127/5), Qi8 = round(Q' * 127/8192)
#define SX_INV 25.4f
#define SQ_INV 0.0155029296875f
#define SCLOGIT 0.07936198f   // (8192/127)*(5/127)/32

typedef short  s16x8 __attribute__((ext_vector_type(8)));
typedef float  f32x4 __attribute__((ext_vector_type(4)));
typedef int    i32x4 __attribute__((ext_vector_type(4)));

// ---- bf16 helpers (RNE) ----------------------------------------------------
__device__ __forceinline__ unsigned short f2bf(float f) {
    unsigned int u = __float_as_uint(f);
    u = (u + 0x7FFFu + ((u >> 16) & 1u)) >> 16;
    return (unsigned short)u;
}
__device__ __forceinline__ float bf2f(unsigned short h) {
    return __uint_as_float(((unsigned int)h) << 16);
}

// ---- async 16B global->LDS -------------------------------------------------
__device__ __forceinline__ void async16(const void* g, void* l) {
    __builtin_amdgcn_global_load_lds(
        (const __attribute__((address_space(1))) unsigned int*)g,
        (__attribute__((address_space(3))) unsigned int*)l, 16, 0, 0);
}

// Stage ROWS x 64-byte rows (row-major, swizzled 16B chunks) into LDS.
// ld in BYTES. 4-wave (256-thread) version.
template<int ROWS>
__device__ __forceinline__ void stage_rows(const char* __restrict__ g,
                                           int ld, char* lds, int wave, int lane) {
#pragma unroll
    for (int r = 0; r < ROWS / 64; ++r) {
        const int row0 = (wave * (ROWS / 64) + r) * 16;   // wave-uniform
        const int r_loc = lane >> 2;
        const int kc = (lane - (lane >> 3)) & 3;          // (slot - r_loc/2) & 3
        const char* gp = g + (size_t)(row0 + r_loc) * ld + kc * 16;
        char* lp = lds + row0 * 64;                       // wave-uniform base
        async16(gp, lp);
    }
}

// 8-wave (512-thread) version. ROWS must be a multiple of 128.
template<int ROWS>
__device__ __forceinline__ void stage_rows8(const char* __restrict__ g,
                                            int ld, char* lds, int wave, int lane) {
#pragma unroll
    for (int r = 0; r < ROWS / 128; ++r) {
        const int row0 = (wave * (ROWS / 128) + r) * 16;  // wave-uniform
        const int r_loc = lane >> 2;
        const int kc = (lane - (lane >> 3)) & 3;
        const char* gp = g + (size_t)(row0 + r_loc) * ld + kc * 16;
        char* lp = lds + row0 * 64;                       // wave-uniform base
        async16(gp, lp);
    }
}

__device__ __forceinline__ int frag_slot(int row, int kc) {
    return (kc + ((row & 15) >> 1)) & 3;
}
__device__ __forceinline__ s16x8 frag_bf16(const char* lds, int row, int kc) {
    return *(const s16x8*)(lds + row * 64 + frag_slot(row, kc) * 16);
}
__device__ __forceinline__ i32x4 frag_i8(const char* lds, int row, int kc) {
    return *(const i32x4*)(lds + row * 64 + frag_slot(row, kc) * 16);
}

// convert 8 fp32 -> bf16 hi/lo and store 16B each to LDS
__device__ __forceinline__ void cvt8_write(float4 a, float4 b, char* hw, char* lw) {
    float fs[8] = {a.x, a.y, a.z, a.w, b.x, b.y, b.z, b.w};
    s16x8 hv, lv;
#pragma unroll
    for (int e = 0; e < 8; ++e) {
        const unsigned short h = f2bf(fs[e]);
        hv[e] = (short)h;
        lv[e] = (short)f2bf(fs[e] - bf2f(h));
    }
    *(s16x8*)hw = hv;
    *(s16x8*)lw = lv;
}

// ---------------------------------------------------------------------------
// Fused dispatch: split-K=4 T-partial GEMM (z<4) + X split (z>=4).
// T = Wk @ Wq^T, 3-pass split bf16, 64x64 tile, K-slice = 256 per z.
// W operands are read as fp32 and split to bf16 hi/lo IN-KERNEL (reg-staged
// cvt + ds_write). The T GEMM is latency-bound with idle VALU, so the cvt
// hides; read bytes unchanged. X-split blocks (BW-bound) overlap the GEMM
// blocks (m114 co-scheduling). grid (16,16,20), 256 threads. (R8 config.)
// ---------------------------------------------------------------------------
__global__ __launch_bounds__(256) void t_fused(
        const float* __restrict__ Wk,   // A source: T = Wk @ Wq^T
        const float* __restrict__ Wq,   // B source
        float* __restrict__ Cpart,
        const float4* __restrict__ X, ushort4* __restrict__ Xhi,
        ushort4* __restrict__ Xlo, char4* __restrict__ Xi8)
{
    constexpr int BM = 64, BN = 64, NCH = 2;
    __shared__ __align__(16) char As_hi[BM * 64 * NCH];
    __shared__ __align__(16) char Bs_hi[BN * 64 * NCH];
    __shared__ __align__(16) char As_lo[BM * 64 * NCH];
    __shared__ __align__(16) char Bs_lo[BN * 64 * NCH];

    const int t = threadIdx.x;
    const int z = blockIdx.z;

    if (z >= 4) {
        // ---- X split branch: 4096 blocks x 256 threads, 1 float4 each ----
        const int idx = (((z - 4) * 256) + blockIdx.y * 16 + blockIdx.x) * 256 + t;
        const float4 v = X[idx];
        ushort4 h, l;
        h.x = f2bf(v.x); l.x = f2bf(v.x - bf2f(h.x));
        h.y = f2bf(v.y); l.y = f2bf(v.y - bf2f(h.y));
        h.z = f2bf(v.z); l.z = f2bf(v.z - bf2f(h.z));
        h.w = f2bf(v.w); l.w = f2bf(v.w - bf2f(h.w));
        Xhi[idx] = h; Xlo[idx] = l;
        char4 c;
        c.x = (signed char)(int)rintf(fminf(fmaxf(v.x * SX_INV, -127.f), 127.f));
        c.y = (signed char)(int)rintf(fminf(fmaxf(v.y * SX_INV, -127.f), 127.f));
        c.z = (signed char)(int)rintf(fminf(fmaxf(v.z * SX_INV, -127.f), 127.f));
        c.w = (signed char)(int)rintf(fminf(fmaxf(v.w * SX_INV, -127.f), 127.f));
        Xi8[idx] = c;
        return;
    }

    // ---- T-partial GEMM branch: K in [z*256, z*256+256) ----
    const int lane = t & 63, wave = t >> 6;
    const int wm = wave >> 1, wn = wave & 1;
    const int m0 = blockIdx.y * BM, n0 = blockIdx.x * BN;

    f32x4 acc[2][2];
#pragma unroll
    for (int i = 0; i < 2; ++i)
#pragma unroll
        for (int j = 0; j < 2; ++j)
#pragma unroll
            for (int r = 0; r < 4; ++r) acc[i][j][r] = 0.f;

    // W staging: thread -> one row/slot; 8 fp32 -> bf16 hi/lo per chunk.
    const int srow = t >> 2, sslot = t & 3;               // 64 rows x 4 slots
    const float* aw = Wk + (size_t)(m0 + srow) * EMBED + sslot * 8;
    const float* bw = Wq + (size_t)(n0 + srow) * EMBED + sslot * 8;
    char* a_hi_w = As_hi + srow * 64 + frag_slot(srow, sslot) * 16;
    char* a_lo_w = As_lo + srow * 64 + frag_slot(srow, sslot) * 16;
    char* b_hi_w = Bs_hi + srow * 64 + frag_slot(srow, sslot) * 16;
    char* b_lo_w = Bs_lo + srow * 64 + frag_slot(srow, sslot) * 16;

    const int kc = lane >> 4;
    const int rr = lane & 15;
    const int kbeg = z * 256;

    for (int k0 = kbeg; k0 < kbeg + 256; k0 += 32 * NCH) {
        // issue all global loads first (latency overlap), then cvt+ds_write
        float4 fa[NCH][2], fb[NCH][2];
#pragma unroll
        for (int c = 0; c < NCH; ++c) {
            fa[c][0] = *(const float4*)(aw + k0 + c * 32);
            fa[c][1] = *(const float4*)(aw + k0 + c * 32 + 4);
            fb[c][0] = *(const float4*)(bw + k0 + c * 32);
            fb[c][1] = *(const float4*)(bw + k0 + c * 32 + 4);
        }
#pragma unroll
        for (int c = 0; c < NCH; ++c) {
            cvt8_write(fa[c][0], fa[c][1], a_hi_w + c * BM * 64, a_lo_w + c * BM * 64);
            cvt8_write(fb[c][0], fb[c][1], b_hi_w + c * BN * 64, b_lo_w + c * BN * 64);
        }
        __syncthreads();

#pragma unroll
        for (int c = 0; c < NCH; ++c) {
            s16x8 ah[2], bh[2], al[2], bl[2];
#pragma unroll
            for (int i = 0; i < 2; ++i)
                ah[i] = frag_bf16(As_hi + c * BM * 64, wm * 32 + i * 16 + rr, kc);
#pragma unroll
            for (int j = 0; j < 2; ++j)
                bh[j] = frag_bf16(Bs_hi + c * BN * 64, wn * 32 + j * 16 + rr, kc);
#pragma unroll
            for (int i = 0; i < 2; ++i)
                al[i] = frag_bf16(As_lo + c * BM * 64, wm * 32 + i * 16 + rr, kc);
#pragma unroll
            for (int j = 0; j < 2; ++j)
                bl[j] = frag_bf16(Bs_lo + c * BN * 64, wn * 32 + j * 16 + rr, kc);

#pragma unroll
            for (int i = 0; i < 2; ++i)
#pragma unroll
                for (int j = 0; j < 2; ++j)
                    acc[i][j] = __builtin_amdgcn_mfma_f32_16x16x32_bf16(ah[i], bh[j], acc[i][j], 0, 0, 0);
#pragma unroll
            for (int i = 0; i < 2; ++i)
#pragma unroll
                for (int j = 0; j < 2; ++j)
                    acc[i][j] = __builtin_amdgcn_mfma_f32_16x16x32_bf16(ah[i], bl[j], acc[i][j], 0, 0, 0);
#pragma unroll
            for (int i = 0; i < 2; ++i)
#pragma unroll
                for (int j = 0; j < 2; ++j)
                    acc[i][j] = __builtin_amdgcn_mfma_f32_16x16x32_bf16(al[i], bh[j], acc[i][j], 0, 0, 0);
        }
        __syncthreads();   // readers done before next iter's ds_writes
    }

    // fp32 partial epilogue into slice z
    const int lr = lane >> 4;
    const int lc = lane & 15;
    float* Cz = Cpart + (size_t)z * EMBED * EMBED;
#pragma unroll
    for (int i = 0; i < 2; ++i)
#pragma unroll
        for (int j = 0; j < 2; ++j)
#pragma unroll
            for (int r = 0; r < 4; ++r) {
                const int row = m0 + wm * 32 + i * 16 + lr * 4 + r;
                const int col = n0 + wn * 32 + j * 16 + lc;
                Cz[(size_t)row * EMBED + col] = acc[i][j][r];
            }
}

// ---------------------------------------------------------------------------
// Merge 4 fp32 T-partials -> split bf16 (Thi, Tlo). 1024 blocks x 256 thr.
// ---------------------------------------------------------------------------
__global__ __launch_bounds__(256) void t_merge(const float4* __restrict__ P,
                                               ushort4* __restrict__ Thi,
                                               ushort4* __restrict__ Tlo) {
    const int idx = blockIdx.x * 256 + threadIdx.x;   // over EMBED*EMBED/4
    const int S = EMBED * EMBED / 4;
    const float4 a = P[idx], b = P[idx + S], c = P[idx + 2 * S], d = P[idx + 3 * S];
    float4 s;
    s.x = (a.x + b.x) + (c.x + d.x);
    s.y = (a.y + b.y) + (c.y + d.y);
    s.z = (a.z + b.z) + (c.z + d.z);
    s.w = (a.w + b.w) + (c.w + d.w);
    ushort4 h, l;
    h.x = f2bf(s.x); l.x = f2bf(s.x - bf2f(h.x));
    h.y = f2bf(s.y); l.y = f2bf(s.y - bf2f(h.y));
    h.z = f2bf(s.z); l.z = f2bf(s.z - bf2f(h.z));
    h.w = f2bf(s.w); l.w = f2bf(s.w - bf2f(h.w));
    Thi[idx] = h; Tlo[idx] = l;
}

// ---------------------------------------------------------------------------
// Qf GEMM: Qf[4096,1024] = X[4096,1024] @ T^T, 3-pass split bf16 (hh+hl+lh).
// ALL operands bf16 in memory, staged via global_load_lds — zero cvt VALU.
// m97-style 2-barrier loop. 512 threads / 8 waves, per-wave 32x32 tile,
// LDS 48 KB. XCD-aware bijective swizzle. Epilogue: fp32 Qf + i8 Qi8.
// (R5 config — measured best. FROZEN this round.)
// ---------------------------------------------------------------------------
__global__ __launch_bounds__(512) void qf_gemm(
        const unsigned short* __restrict__ Ahi, const unsigned short* __restrict__ Alo,
        const unsigned short* __restrict__ Bhi, const unsigned short* __restrict__ Blo,
        float* __restrict__ C, signed char* __restrict__ Ci8)
{
    constexpr int BM = 128, BN = 64, NCH = 2;             // K-step = 64
    __shared__ __align__(16) char As_hi[BM * 64 * NCH];   // 16 KB
    __shared__ __align__(16) char As_lo[BM * 64 * NCH];   // 16 KB
    __shared__ __align__(16) char Bs_hi[BN * 64 * NCH];   // 8 KB
    __shared__ __align__(16) char Bs_lo[BN * 64 * NCH];   // 8 KB

    const int t = threadIdx.x;
    const int lane = t & 63, wave = t >> 6;
    const int wm = wave >> 1, wn = wave & 1;              // 4x2 wave grid

    // XCD swizzle: 512 blocks = 8 XCD x 64; per XCD 4 m-panels x 16 n-tiles
    const int bid = blockIdx.y * 16 + blockIdx.x;
    const int g = bid & 7, ii = bid >> 3;                 // ii in 0..63
    const int m0 = (g * 4 + (ii >> 4)) * BM;
    const int n0 = (ii & 15) * BN;

    f32x4 acc[2][2];
#pragma unroll
    for (int i = 0; i < 2; ++i)
#pragma unroll
        for (int j = 0; j < 2; ++j)
#pragma unroll
            for (int r = 0; r < 4; ++r) acc[i][j][r] = 0.f;

    const char* ah_g = (const char*)(Ahi + (size_t)m0 * EMBED);
    const char* al_g = (const char*)(Alo + (size_t)m0 * EMBED);

    // B staging: waves 0-3 stage Bs_hi, waves 4-7 stage Bs_lo (16 rows each)
    const unsigned short* bsrc = (wave < 4) ? Bhi : Blo;
    char* bdst = (wave < 4) ? Bs_hi : Bs_lo;
    const int w4 = wave & 3;
    const int brow0 = w4 * 16;
    const int b_rloc = lane >> 2;
    const int b_kc = (lane - (lane >> 3)) & 3;
    const char* bg = (const char*)(bsrc + (size_t)(n0 + brow0 + b_rloc) * EMBED) + b_kc * 16;
    char* b_lds = bdst + brow0 * 64;                      // wave-uniform

    const int kc = lane >> 4;
    const int rr = lane & 15;

    for (int k0 = 0; k0 < EMBED; k0 += 32 * NCH) {
#pragma unroll
        for (int c = 0; c < NCH; ++c) {
            const int kb = (k0 + 32 * c) * 2;
            stage_rows8<BM>(ah_g + kb, EMBED * 2, As_hi + c * BM * 64, wave, lane);
            stage_rows8<BM>(al_g + kb, EMBED * 2, As_lo + c * BM * 64, wave, lane);
            async16(bg + kb, b_lds + c * BN * 64);
        }
        __syncthreads();

#pragma unroll
        for (int c = 0; c < NCH; ++c) {
            s16x8 ah[2], bh[2], al[2], bl[2];
#pragma unroll
            for (int i = 0; i < 2; ++i)
                ah[i] = frag_bf16(As_hi + c * BM * 64, wm * 32 + i * 16 + rr, kc);
#pragma unroll
            for (int j = 0; j < 2; ++j)
                bh[j] = frag_bf16(Bs_hi + c * BN * 64, wn * 32 + j * 16 + rr, kc);
#pragma unroll
            for (int i = 0; i < 2; ++i)
                al[i] = frag_bf16(As_lo + c * BM * 64, wm * 32 + i * 16 + rr, kc);
#pragma unroll
            for (int j = 0; j < 2; ++j)
                bl[j] = frag_bf16(Bs_lo + c * BN * 64, wn * 32 + j * 16 + rr, kc);

#pragma unroll
            for (int i = 0; i < 2; ++i)
#pragma unroll
                for (int j = 0; j < 2; ++j)
                    acc[i][j] = __builtin_amdgcn_mfma_f32_16x16x32_bf16(ah[i], bh[j], acc[i][j], 0, 0, 0);
#pragma unroll
            for (int i = 0; i < 2; ++i)
#pragma unroll
                for (int j = 0; j < 2; ++j)
                    acc[i][j] = __builtin_amdgcn_mfma_f32_16x16x32_bf16(ah[i], bl[j], acc[i][j], 0, 0, 0);
#pragma unroll
            for (int i = 0; i < 2; ++i)
#pragma unroll
                for (int j = 0; j < 2; ++j)
                    acc[i][j] = __builtin_amdgcn_mfma_f32_16x16x32_bf16(al[i], bh[j], acc[i][j], 0, 0, 0);
        }
        __syncthreads();
    }

    // Epilogue: C/D layout col=lane&15, row=(lane>>4)*4+reg
    const int lr = lane >> 4;
    const int lc = lane & 15;
#pragma unroll
    for (int i = 0; i < 2; ++i)
#pragma unroll
        for (int j = 0; j < 2; ++j)
#pragma unroll
            for (int r = 0; r < 4; ++r) {
                const int row = m0 + wm * 32 + i * 16 + lr * 4 + r;
                const int col = n0 + wn * 32 + j * 16 + lc;
                const float v = acc[i][j][r];
                const size_t idx = (size_t)row * EMBED + col;
                C[idx] = v;
                const float q = fminf(fmaxf(v * SQ_INV, -127.f), 127.f);
                Ci8[idx] = (signed char)(int)rintf(q);
            }
}

// ---------------------------------------------------------------------------
// i8 scores GEMM + write-only candidate selection.
// NEW (T3/T4): counted-vmcnt double-buffered pipeline. K-step 64, full LDS
// dbuf at the SAME 48 KB (2x(16+8) KB) -> occupancy unchanged. Per step each
// lane issues exactly 3 global_load_lds into buf[nxt], then waits
// s_waitcnt vmcnt(3) (current buffer's loads done; next's 3 REMAIN IN FLIGHT
// across the barrier — the counted-vmcnt lever __syncthreads cannot express),
// raw s_barrier, compute, raw s_barrier (protects buf[nxt... cur^1] from the
// next step's re-stage). Tile 256x128, 512 thr / 8 waves, XCD swizzle,
// selection epilogue byte-identical to R4-R8.
// ---------------------------------------------------------------------------
__global__ __launch_bounds__(512, 4) void gemm_i8_scores(
        const signed char* __restrict__ A,   // Qi8 [NTOK, EMBED]
        const signed char* __restrict__ B,   // Xi8 [NTOK, EMBED]
        float* __restrict__ tmax, int* __restrict__ cnts, int2* __restrict__ cand)
{
    __shared__ __align__(16) char As[2][256 * 64];    // 2 x 16 KB
    __shared__ __align__(16) char Bs[2][128 * 64];    // 2 x 8 KB

    const int t = threadIdx.x;
    const int lane = t & 63, wave = t >> 6;
    const int wm = wave >> 1, wn = wave & 1;          // 4x2 wave grid

    // XCD swizzle: 512 blocks = 8 XCD x 64; per XCD 2 m-panels x 32 n-tiles
    const int bid = blockIdx.y * 32 + blockIdx.x;
    const int g = bid & 7, ii = bid >> 3;             // ii in 0..63
    const int by = g * 2 + (ii >> 5);
    const int bx = ii & 31;
    const int m0 = by * 256, n0 = bx * 128;

    i32x4 acc[4][4];
#pragma unroll
    for (int i = 0; i < 4; ++i)
#pragma unroll
        for (int j = 0; j < 4; ++j)
#pragma unroll
            for (int r = 0; r < 4; ++r) acc[i][j][r] = 0;

    const char* a_g = (const char*)A + (size_t)m0 * EMBED;
    const char* b_g = (const char*)B + (size_t)n0 * EMBED;
    const int kc = lane >> 4;
    const int rr = lane & 15;

    // prologue: stage step 0 into buf 0 (3 loads/lane)
    stage_rows8<256>(a_g, EMBED, As[0], wave, lane);
    stage_rows8<128>(b_g, EMBED, Bs[0], wave, lane);

    for (int s = 0; s < 16; ++s) {
        const int cur = s & 1;
        if (s < 15) {
            // stage step s+1 into buf[cur^1] (3 loads/lane)
            stage_rows8<256>(a_g + (s + 1) * 64, EMBED, As[cur ^ 1], wave, lane);
            stage_rows8<128>(b_g + (s + 1) * 64, EMBED, Bs[cur ^ 1], wave, lane);
            // wait only for buf[cur]'s 3 loads; next's 3 stay in flight
            asm volatile("s_waitcnt vmcnt(3)" ::: "memory");
        } else {
            asm volatile("s_waitcnt vmcnt(0)" ::: "memory");
        }
        __builtin_amdgcn_s_barrier();    // buf[cur] valid for all waves

        i32x4 af[4], bf[4];
#pragma unroll
        for (int i = 0; i < 4; ++i) af[i] = frag_i8(As[cur], wm * 64 + i * 16 + rr, kc);
#pragma unroll
        for (int j = 0; j < 4; ++j) bf[j] = frag_i8(Bs[cur], wn * 64 + j * 16 + rr, kc);
#pragma unroll
        for (int i = 0; i < 4; ++i)
#pragma unroll
            for (int j = 0; j < 4; ++j)
                acc[i][j] = __builtin_amdgcn_mfma_i32_16x16x64_i8(af[i], bf[j], acc[i][j], 0, 0, 0);

        __builtin_amdgcn_s_barrier();    // readers of buf[cur] done before
                                         // step s+1 re-stages into buf[cur]
    }

    // Write-only local selection epilogue (per-wave 64x64 — unchanged).
    const int lr = lane >> 4;
    const int lc = lane & 15;
    const int wslot = bx * 2 + wn;                    // 64 slots per row
    const unsigned long long grp = 0xFFFFull << (lr * 16);
    const unsigned long long low = (lane == 63) ? 0x7FFFFFFFFFFFFFFFull
                                                : ((1ull << lane) - 1);
#pragma unroll
    for (int i = 0; i < 4; ++i)
#pragma unroll
        for (int r = 0; r < 4; ++r) {
            const int row = m0 + wm * 64 + i * 16 + lr * 4 + r;
            float v[4];
            float vmax = -3.4e38f;
#pragma unroll
            for (int j = 0; j < 4; ++j) {
                v[j] = (float)acc[i][j][r] * SCLOGIT;
                vmax = fmaxf(vmax, v[j]);
            }
#pragma unroll
            for (int msk = 1; msk < 16; msk <<= 1)
                vmax = fmaxf(vmax, __shfl_xor(vmax, msk, 64));
            const float thr = vmax - MARGIN;
            int base = 0;
#pragma unroll
            for (int j = 0; j < 4; ++j) {
                const bool pred = v[j] > thr;
                const unsigned long long m = __ballot(pred) & grp;
                if (pred) {
                    const int pos = base + __popcll(m & low);
                    if (pos < KC)
                        cand[((size_t)row * 64 + wslot) * KC + pos] =
                            make_int2(n0 + wn * 64 + j * 16 + lc,
                                      __float_as_int(v[j]));
                }
                base += __popcll(m);
            }
            if (lc == 0) {
                tmax[(size_t)row * 64 + wslot] = vmax;
                cnts[(size_t)row * 64 + wslot] = base < KC ? base : KC;
            }
        }
}

// ---------------------------------------------------------------------------
// Final: global row max, filter candidates, wave-parallel exact logits,
// parallel weight precompute, weight-skip blend. (R11 config — neutral but
// not harmful.) 1 block/row.
// ---------------------------------------------------------------------------
__global__ __launch_bounds__(256) void sparse_out(const float* __restrict__ tmax,
                                                  const int* __restrict__ cnts,
                                                  const int2* __restrict__ cand,
                                                  const float* __restrict__ Qf,
                                                  const float* __restrict__ X,
                                                  float* __restrict__ out) {
    const int t = threadIdx.x;
    const int lane = t & 63, wave = t >> 6;
    const int row = blockIdx.x;

    __shared__ float gmax_s;
    __shared__ int   n2;
    __shared__ int   list[CAP];
    __shared__ float ll[CAP];
    __shared__ float wl[CAP];
    __shared__ float mt_s;
    if (t == 0) n2 = 0;

    // global row max over 64 tile maxima (wave 0)
    float gm = -3.4e38f;
    if (t < 64) gm = tmax[(size_t)row * 64 + t];
#pragma unroll
    for (int off = 32; off >= 1; off >>= 1) gm = fmaxf(gm, __shfl_xor(gm, off, 64));
    if (t == 0) gmax_s = gm;
    __syncthreads();
    const float thr = gmax_s - MARGIN;

    // filter stored candidates (64 slots x KC entries)
    for (int e = t; e < 64 * KC; e += 256) {
        const int s = e >> 3, k = e & (KC - 1);
        if (k < cnts[(size_t)row * 64 + s]) {
            const int2 c = cand[((size_t)row * 64 + s) * KC + k];
            if (__int_as_float(c.y) > thr) {
                const int p = atomicAdd(&n2, 1);   // LDS atomic
                if (p < CAP) list[p] = c.x;
            }
        }
    }
    __syncthreads();
    const int nc = min(n2, CAP);

    // exact logits, wave-parallel: candidate c handled by wave (c & 3)
    float4 q[4];
#pragma unroll
    for (int i = 0; i < 4; ++i)
        q[i] = *(const float4*)&Qf[(size_t)row * EMBED + lane * 16 + i * 4];
    for (int c = wave; c < nc; c += 4) {
        const float* xp = &X[(size_t)list[c] * EMBED + lane * 16];
        float p = 0.f;
#pragma unroll
        for (int i = 0; i < 4; ++i) {
            const float4 x4 = *(const float4*)(xp + i * 4);
            p += q[i].x * x4.x + q[i].y * x4.y + q[i].z * x4.z + q[i].w * x4.w;
        }
#pragma unroll
        for (int off = 32; off >= 1; off >>= 1) p += __shfl_xor(p, off, 64);
        if (lane == 0) ll[c] = p * 0.03125f;
    }
    __syncthreads();

    // mt = max logit (wave 0 reduce), then parallel weight fill
    if (t < 64) {
        float m = -3.4e38f;
        for (int c = t; c < nc; c += 64) m = fmaxf(m, ll[c]);
#pragma unroll
        for (int off = 32; off >= 1; off >>= 1) m = fmaxf(m, __shfl_xor(m, off, 64));
        if (t == 0) mt_s = m;
    }
    __syncthreads();
    const float mt = mt_s;
    if (t < CAP) wl[t] = (t < nc) ? __expf(ll[t] - mt) : 0.f;
    __syncthreads();

    // wsum from LDS (broadcast reads, no exp)
    float wsum = 0.f;
    for (int c = 0; c < nc; ++c) wsum += wl[c];
    const float inv = 1.0f / wsum;
    const float wthr = wsum * 1e-7f;     // uniform skip threshold

    float4 o = {0.f, 0.f, 0.f, 0.f};
    for (int c = 0; c < nc; ++c) {
        const float w = wl[c];
        if (w < wthr) continue;          // block-uniform branch (LDS value)
        const float4 xj = *(const float4*)&X[(size_t)list[c] * EMBED + t * 4];
        o.x += w * xj.x; o.y += w * xj.y; o.z += w * xj.z; o.w += w * xj.w;
    }
    o.x *= inv; o.y *= inv; o.z *= inv; o.w *= inv;
    *(float4*)&out[(size_t)row * EMBED + t * 4] = o;
}

extern "C" void kernel_launch(void* const* d_in, const int* in_sizes, int n_in,
                              void* d_out, int out_size, void* d_ws, size_t ws_size,
                              hipStream_t stream) {
    const float* X  = (const float*)d_in[0];  // [4096,1024]
    const float* Wq = (const float*)d_in[1];  // [1024,1024]
    const float* Wk = (const float*)d_in[2];  // [1024,1024]
    float* out = (float*)d_out;

    char* ws = (char*)d_ws;
    const size_t MB = 1024 * 1024;
    unsigned short* Xhi = (unsigned short*)(ws + 0 * MB);   // 8 MB
    unsigned short* Xlo = (unsigned short*)(ws + 8 * MB);   // 8 MB
    signed char*    Xi8 = (signed char*)(ws + 16 * MB);     // 4 MB
    float*          Qf  = (float*)(ws + 20 * MB);           // 16 MB
    signed char*    Qi8 = (signed char*)(ws + 36 * MB);     // 4 MB
    float* tmax = (float*)(ws + 40 * MB);                   // 1 MB
    int*   cnts = (int*)(ws + 41 * MB);                     // 1 MB
    int2*  cand = (int2*)(ws + 42 * MB);                    // 16 MB
    unsigned short* Thi  = (unsigned short*)(ws + 66 * MB);
    unsigned short* Tlo  = (unsigned short*)(ws + 68 * MB);
    // T fp32 partials (4 x 4 MB) alias the cand region: written/consumed
    // (t_fused -> t_merge) strictly before gemm_i8_scores writes cand.
    float* Tpart = (float*)(ws + 42 * MB);                  // 16 MB

    // 1) fused: split-K=4 T-partials with in-kernel W split (z<4)
    //    + X split (z>=4, overlapped)
    t_fused<<<dim3(16, 16, 20), 256, 0, stream>>>(
        Wk, Wq, Tpart,
        (const float4*)X, (ushort4*)Xhi, (ushort4*)Xlo, (char4*)Xi8);

    // 2) merge partials -> split bf16 T
    t_merge<<<1024, 256, 0, stream>>>((const float4*)Tpart,
                                      (ushort4*)Thi, (ushort4*)Tlo);

    // 3) Qf = X @ T^T (= X @ M): all-bf16 global_load_lds, 8 waves, 48 KB
    qf_gemm<<<dim3(16, 32), 512, 0, stream>>>(
        Xhi, Xlo, Thi, Tlo, Qf, Qi8);

    // 4) i8 cheap scores (256x128, counted-vmcnt dbuf pipeline, K-step 64)
    gemm_i8_scores<<<dim3(32, 16), 512, 0, stream>>>(Qi8, Xi8, tmax, cnts, cand);

    // 5) exact sparse softmax + gather
    sparse_out<<<NTOK, 256, 0, stream>>>(tmax, cnts, cand, Qf, X, out);
}